// Round 14
// baseline (436.954 us; speedup 1.0000x reference)
//
#include <hip/hip_runtime.h>
#include <stdint.h>

typedef __attribute__((ext_vector_type(8))) short short8;
typedef __attribute__((ext_vector_type(4))) short short4v;
typedef __attribute__((ext_vector_type(4))) float f32x4;

#define DEV static __device__ __forceinline__

static constexpr int LL = 2048;
static constexpr int DD = 1024;
static constexpr long long BLD = 8388608LL; // 4*2048*1024

DEV short f2bf(float f) {
    uint32_t u = __builtin_bit_cast(uint32_t, f);
    u += 0x7fffu + ((u >> 16) & 1u);   // RNE
    return (short)(u >> 16);
}
DEV float bf2f(short s) {
    uint32_t u = ((uint32_t)(uint16_t)s) << 16;
    return __builtin_bit_cast(float, u);
}

DEV float waveSum(float v) {
#pragma unroll
    for (int o = 32; o; o >>= 1) v += __shfl_down(v, o);
    return v;
}
DEV float waveMax(float v) {
#pragma unroll
    for (int o = 32; o; o >>= 1) v = fmaxf(v, __shfl_down(v, o));
    return v;
}

DEV void gload16(const void* g, void* l) {
    __builtin_amdgcn_global_load_lds(
        (const __attribute__((address_space(1))) uint32_t*)(uintptr_t)g,
        (__attribute__((address_space(3))) uint32_t*)(uintptr_t)l,
        16, 0, 0);
}

// ---------------- elementwise / reduction kernels ----------------

__global__ __launch_bounds__(256) void k_zero1(float* p) {
    if (threadIdx.x == 0) *p = 0.f;
}

__global__ __launch_bounds__(256) void k_f32_to_bf16(const float* __restrict__ in,
                                                     short* __restrict__ out, int n8) {
    int i = blockIdx.x * 256 + threadIdx.x;
    if (i >= n8) return;
    const float4* p = (const float4*)(in + (long long)i * 8);
    float4 a = p[0], b = p[1];
    short8 o;
    o[0] = f2bf(a.x); o[1] = f2bf(a.y); o[2] = f2bf(a.z); o[3] = f2bf(a.w);
    o[4] = f2bf(b.x); o[5] = f2bf(b.y); o[6] = f2bf(b.z); o[7] = f2bf(b.w);
    *(short8*)(out + (long long)i * 8) = o;
}

// convert 8 D*D fp32 weights to bf16 destinations in one launch (512 blocks each)
__global__ __launch_bounds__(256) void k_wcat(
    const float* wq, const float* wk, const float* wv,
    const float* pq, const float* pk, const float* pv,
    const float* wg, const float* wo,
    short* Wqkv, short* Pqkv, short* Wg, short* Wo) {
    const int bid = blockIdx.x;            // 4096 blocks
    const int w = bid >> 9;                // which weight
    const long long i = (long long)((bid & 511) * 256 + threadIdx.x) * 8;
    const float* src; short* dst;
    switch (w) {
        case 0: src = wq; dst = Wqkv;                break;
        case 1: src = wk; dst = Wqkv + 1048576;      break;
        case 2: src = wv; dst = Wqkv + 2097152;      break;
        case 3: src = pq; dst = Pqkv;                break;
        case 4: src = pk; dst = Pqkv + 1048576;      break;
        case 5: src = pv; dst = Pqkv + 2097152;      break;
        case 6: src = wg; dst = Wg;                  break;
        default: src = wo; dst = Wo;                 break;
    }
    const float4* p = (const float4*)(src + i);
    float4 a = p[0], b = p[1];
    short8 o;
    o[0] = f2bf(a.x); o[1] = f2bf(a.y); o[2] = f2bf(a.z); o[3] = f2bf(a.w);
    o[4] = f2bf(b.x); o[5] = f2bf(b.y); o[6] = f2bf(b.z); o[7] = f2bf(b.w);
    *(short8*)(dst + i) = o;
}

// concat 6 length-1024 fp32 bias vectors into bqkv[3072] and bpw[3072]
__global__ __launch_bounds__(256) void k_biascat(
    const float* bq, const float* bk, const float* bv,
    const float* pq, const float* pk, const float* pv,
    float* bqkv, float* bpw) {
    const int idx = blockIdx.x * 256 + threadIdx.x;  // 24 blocks -> 6144
    const int sel = idx >> 10, j = idx & 1023;
    const float* s;
    switch (sel) {
        case 0: s = bq; break; case 1: s = bk; break; case 2: s = bv; break;
        case 3: s = pq; break; case 4: s = pk; break; default: s = pv; break;
    }
    float v = s[j];
    if (sel < 3) bqkv[sel * 1024 + j] = v;
    else         bpw[(sel - 3) * 1024 + j] = v;
}

// fused depthwise conv over L (k=3, pad 1) + bias, all 3 branches.
// Each thread: one 8-channel chunk x 8 consecutive L rows (register sliding
// window); weights as 6x float4 + 2x float4 -> 26 coalesced VMEM/8 rows.
__global__ __launch_bounds__(256) void k_dwconv3b(const short* __restrict__ in,
                                                  const float* __restrict__ dwq,
                                                  const float* __restrict__ dwk,
                                                  const float* __restrict__ dwv,
                                                  const float* __restrict__ dbq,
                                                  const float* __restrict__ dbk,
                                                  const float* __restrict__ dbv,
                                                  short* __restrict__ outp) {
    const int idx = blockIdx.x * 256 + threadIdx.x;  // 3*4*256*128 = 393216
    const int d8 = idx & 127;
    const int lc = (idx >> 7) & 255;
    const int b  = (idx >> 15) & 3;
    const int br = idx >> 17;                         // uniform per block
    const float* dw = (br == 0) ? dwq : (br == 1) ? dwk : dwv;
    const float* db = (br == 0) ? dbq : (br == 1) ? dbk : dbv;

    float w[24], bb[8];
    {
        const float4* wp = (const float4*)(dw + d8 * 24);
#pragma unroll
        for (int i = 0; i < 6; i++) {
            float4 t = wp[i];
            w[i * 4 + 0] = t.x; w[i * 4 + 1] = t.y;
            w[i * 4 + 2] = t.z; w[i * 4 + 3] = t.w;
        }
        const float4* bp = (const float4*)(db + d8 * 8);
        float4 t0 = bp[0], t1 = bp[1];
        bb[0] = t0.x; bb[1] = t0.y; bb[2] = t0.z; bb[3] = t0.w;
        bb[4] = t1.x; bb[5] = t1.y; bb[6] = t1.z; bb[7] = t1.w;
    }

    const int l0 = lc * 8;
    const long long base = ((long long)(b * LL + l0)) * 3072 + br * 1024 + d8 * 8;
    short8 xr[10];
#pragma unroll
    for (int i = 0; i < 10; i++) {
        const int l = l0 - 1 + i;
        if (l >= 0 && l < LL) xr[i] = *(const short8*)(in + base + (long long)(i - 1) * 3072);
        else { short8 z = {0, 0, 0, 0, 0, 0, 0, 0}; xr[i] = z; }
    }
#pragma unroll
    for (int j = 0; j < 8; j++) {
        short8 o;
#pragma unroll
        for (int c = 0; c < 8; c++) {
            float v = bb[c] + w[c * 3 + 0] * bf2f(xr[j][c])
                            + w[c * 3 + 1] * bf2f(xr[j + 1][c])
                            + w[c * 3 + 2] * bf2f(xr[j + 2][c]);
            o[c] = f2bf(v);
        }
        *(short8*)(outp + base + (long long)j * 3072) = o;
    }
}

// in-place row L2 normalize, row = blockIdx.x, D=1024, 256 thr * 4
__global__ __launch_bounds__(256) void k_l2norm(short* __restrict__ xp) {
    __shared__ float red[4];
    const long long row = blockIdx.x;
    short* p = xp + row * DD;
    const int t = threadIdx.x;
    short4v v = *(short4v*)(p + t * 4);
    float f0 = bf2f(v[0]), f1 = bf2f(v[1]), f2 = bf2f(v[2]), f3 = bf2f(v[3]);
    float ss = f0 * f0 + f1 * f1 + f2 * f2 + f3 * f3;
    ss = waveSum(ss);
    if ((t & 63) == 0) red[t >> 6] = ss;
    __syncthreads();
    ss = (red[0] + red[1]) + (red[2] + red[3]);
    float s = 1.f / fmaxf(sqrtf(ss), 1e-12f);
    v[0] = f2bf(f0 * s); v[1] = f2bf(f1 * s); v[2] = f2bf(f2 * s); v[3] = f2bf(f3 * s);
    *(short4v*)(p + t * 4) = v;
}

// in-place row softmax, width 2048 bf16, row = blockIdx.x
__global__ __launch_bounds__(256) void k_softmax(short* __restrict__ sp) {
    __shared__ float redM[4], redS[4];
    const long long row = blockIdx.x;
    short* p = sp + row * 2048;
    const int t = threadIdx.x;
    short8 v = *(short8*)(p + t * 8);
    float f[8];
    float m = -3.0e38f;
#pragma unroll
    for (int j = 0; j < 8; j++) { f[j] = bf2f(v[j]); m = fmaxf(m, f[j]); }
    m = waveMax(m);
    if ((t & 63) == 0) redM[t >> 6] = m;
    __syncthreads();
    m = fmaxf(fmaxf(redM[0], redM[1]), fmaxf(redM[2], redM[3]));
    float s = 0.f;
#pragma unroll
    for (int j = 0; j < 8; j++) { f[j] = __expf(f[j] - m); s += f[j]; }
    s = waveSum(s);
    if ((t & 63) == 0) redS[t >> 6] = s;
    __syncthreads();
    s = (redS[0] + redS[1]) + (redS[2] + redS[3]);
    float inv = 1.f / s;
#pragma unroll
    for (int j = 0; j < 8; j++) v[j] = f2bf(f[j] * inv);
    *(short8*)(p + t * 8) = v;
}

// in-place layernorm on fp32 rows of 1024
__global__ __launch_bounds__(256) void k_layernorm(float* __restrict__ y,
                                                   const float* __restrict__ g,
                                                   const float* __restrict__ b) {
    __shared__ float redS[4], redQ[4];
    const long long row = blockIdx.x;
    float* p = y + row * DD;
    const int t = threadIdx.x;
    float4 v = *(float4*)(p + t * 4);
    float s = v.x + v.y + v.z + v.w;
    float q = v.x * v.x + v.y * v.y + v.z * v.z + v.w * v.w;
    s = waveSum(s); q = waveSum(q);
    if ((t & 63) == 0) { redS[t >> 6] = s; redQ[t >> 6] = q; }
    __syncthreads();
    s = (redS[0] + redS[1]) + (redS[2] + redS[3]);
    q = (redQ[0] + redQ[1]) + (redQ[2] + redQ[3]);
    float mu = s * (1.f / DD);
    float var = q * (1.f / DD) - mu * mu;
    float rs = rsqrtf(var + 1e-5f);
    float4 o;
    o.x = (v.x - mu) * rs * g[t * 4 + 0] + b[t * 4 + 0];
    o.y = (v.y - mu) * rs * g[t * 4 + 1] + b[t * 4 + 1];
    o.z = (v.z - mu) * rs * g[t * 4 + 2] + b[t * 4 + 2];
    o.w = (v.w - mu) * rs * g[t * 4 + 3] + b[t * 4 + 3];
    *(float4*)(p + t * 4) = o;
}

// 64x64 LDS-tiled transpose, bf16 -> bf16, per-batch via blockIdx.z
__global__ __launch_bounds__(256) void k_transpose_bf16(const short* __restrict__ in,
                                                        short* __restrict__ out,
                                                        int rows, int cols) {
    __shared__ short tile[64][65];
    const long long boff = (long long)blockIdx.z * rows * cols;
    in += boff; out += boff;
    const int r0 = blockIdx.y * 64, c0 = blockIdx.x * 64;
    const int t = threadIdx.x;
#pragma unroll
    for (int i = 0; i < 16; i++) {
        int lin = i * 256 + t; int lr = lin >> 6, lc = lin & 63;
        tile[lr][lc] = in[(long long)(r0 + lr) * cols + (c0 + lc)];
    }
    __syncthreads();
#pragma unroll
    for (int i = 0; i < 16; i++) {
        int lin = i * 256 + t; int orr = lin >> 6, oc = lin & 63;
        out[(long long)(c0 + orr) * rows + (r0 + oc)] = tile[oc][orr];
    }
}

// 64x64 LDS-tiled transpose, fp32 -> bf16 (for mem_w^T)
__global__ __launch_bounds__(256) void k_transpose_f32_bf16(const float* __restrict__ in,
                                                            short* __restrict__ out,
                                                            int rows, int cols) {
    __shared__ float tile[64][65];
    const int r0 = blockIdx.y * 64, c0 = blockIdx.x * 64;
    const int t = threadIdx.x;
#pragma unroll
    for (int i = 0; i < 16; i++) {
        int lin = i * 256 + t; int lr = lin >> 6, lc = lin & 63;
        tile[lr][lc] = in[(long long)(r0 + lr) * cols + (c0 + lc)];
    }
    __syncthreads();
#pragma unroll
    for (int i = 0; i < 16; i++) {
        int lin = i * 256 + t; int orr = lin >> 6, oc = lin & 63;
        out[(long long)(c0 + orr) * rows + (r0 + oc)] = f2bf(tile[oc][orr]);
    }
}

enum { EPI_SILU, EPI_BIAS, EPI_SCALE, EPI_PLAIN, EPI_GATE, EPI_RESID, EPI_MLOSS };

// ======== R14 gemm256c: 256x128 tile, 4 waves of 128x64, 2 waves/SIMD =====
// R12 geometry (the right one: wave tile 128x64 -> 42.7 FLOP per LDS-read-
// byte vs 64x64's 32) with the REGISTER-LEGAL occupancy: acc[8][4] = 128
// AGPR + ~84 arch = 212 unified regs/wave -> fits the 2-waves/SIMD budget
// (256), NOT 3 (170 -> R12's 774 MB spill).  __launch_bounds__(256,2) ->
// 2 blocks/CU (LDS 2x48 KiB), 8 waves/CU.  Serialized single-buffer loop
// (stage; vmcnt(0); barrier; reads+MFMA; barrier) — overlap via 2 co-resident
// blocks.  Swizzle: R9/R11-proven conflict-free (128 B rows, 8 chunks,
// chunk c at physical c^(row&7); linear gload_lds dest + pre-swizzled
// global source + same involution on ds_read).
template <int EPI>
__global__ __launch_bounds__(256, 2) void gemm256c(
    const short* __restrict__ A, int lda, long long sAb,
    const short* __restrict__ W, int ldw, long long sWb,
    void* __restrict__ outv, int ldo, long long sOb,
    const float* __restrict__ bias, long long sBias,
    int K, float scale) {
    __shared__ short lds[24576];       // A [256][64] + B [128][64] = 48 KiB

    const int z = blockIdx.z;
    A += (long long)z * sAb;
    W += (long long)z * sWb;

    const int tid = threadIdx.x;
    const int wid = tid >> 6, lane = tid & 63;
    const int row0 = blockIdx.y * 256, col0 = blockIdx.x * 128;
    const int wrM = (wid >> 1) * 128, wcN = (wid & 1) * 64;
    const int rl = lane & 15, kcl = lane >> 4;

    f32x4 acc[8][4] = {};

    // staging: 8 threads/row (128 B line), source chunk pre-swizzled
    const int srow = tid >> 3;                       // 0..31
    const int cswz = (tid & 7) ^ (srow & 7);
    long long offA[8], offB[4];
#pragma unroll
    for (int j = 0; j < 8; j++)
        offA[j] = (long long)(row0 + j * 32 + srow) * lda + cswz * 8;
#pragma unroll
    for (int j = 0; j < 4; j++)
        offB[j] = (long long)(col0 + j * 32 + srow) * ldw + cswz * 8;

    const int nk = K >> 6;
    const int swz0 = (kcl ^ (rl & 7)) * 8;
    const int swz1 = ((kcl + 4) ^ (rl & 7)) * 8;

    for (int t = 0; t < nk; ++t) {
        const short* a = A + (long long)t * 64;
        const short* w = W + (long long)t * 64;
#pragma unroll
        for (int j = 0; j < 8; j++)
            gload16(a + offA[j], lds + (j * 256 + tid) * 8);
#pragma unroll
        for (int j = 0; j < 4; j++)
            gload16(w + offB[j], lds + 16384 + (j * 256 + tid) * 8);
        asm volatile("s_waitcnt vmcnt(0)" ::: "memory");
        __builtin_amdgcn_s_barrier();

        short8 af[8], bfr[4];
        // ---- ks = 0 ----
#pragma unroll
        for (int mi = 0; mi < 8; mi++)
            af[mi] = *(const short8*)&lds[(wrM + mi * 16 + rl) * 64 + swz0];
#pragma unroll
        for (int ni = 0; ni < 4; ni++)
            bfr[ni] = *(const short8*)&lds[16384 + (wcN + ni * 16 + rl) * 64 + swz0];
        __builtin_amdgcn_s_setprio(1);
#pragma unroll
        for (int mi = 0; mi < 8; mi++)
#pragma unroll
            for (int ni = 0; ni < 4; ni++)
                acc[mi][ni] = __builtin_amdgcn_mfma_f32_16x16x32_bf16(
                    af[mi], bfr[ni], acc[mi][ni], 0, 0, 0);
        __builtin_amdgcn_s_setprio(0);
        // ---- ks = 1 ----
#pragma unroll
        for (int mi = 0; mi < 8; mi++)
            af[mi] = *(const short8*)&lds[(wrM + mi * 16 + rl) * 64 + swz1];
#pragma unroll
        for (int ni = 0; ni < 4; ni++)
            bfr[ni] = *(const short8*)&lds[16384 + (wcN + ni * 16 + rl) * 64 + swz1];
        __builtin_amdgcn_s_setprio(1);
#pragma unroll
        for (int mi = 0; mi < 8; mi++)
#pragma unroll
            for (int ni = 0; ni < 4; ni++)
                acc[mi][ni] = __builtin_amdgcn_mfma_f32_16x16x32_bf16(
                    af[mi], bfr[ni], acc[mi][ni], 0, 0, 0);
        __builtin_amdgcn_s_setprio(0);
        __builtin_amdgcn_s_barrier();    // all reads of tile t done before t+1 stages
    }

    // epilogue: C/D layout col=lane&15, row=(lane>>4)*4+r  [m89/m91-verified]
    const int lr4 = (lane >> 4) * 4;
    float bcol[4];
    if constexpr (EPI == EPI_SILU || EPI == EPI_BIAS) {
        const float* bz = bias + (long long)z * sBias;
#pragma unroll
        for (int ni = 0; ni < 4; ni++) bcol[ni] = bz[col0 + wcN + ni * 16 + rl];
    }
    short* op = (short*)outv + (long long)z * sOb;
#pragma unroll
    for (int mi = 0; mi < 8; mi++) {
#pragma unroll
        for (int ni = 0; ni < 4; ni++) {
            const int gc = col0 + wcN + ni * 16 + rl;
#pragma unroll
            for (int r = 0; r < 4; r++) {
                const int gr = row0 + wrM + mi * 16 + lr4 + r;
                float v = acc[mi][ni][r];
                if constexpr (EPI == EPI_SILU) {
                    v += bcol[ni];
                    v = v / (1.f + __expf(-v));
                } else if constexpr (EPI == EPI_BIAS) {
                    v += bcol[ni];
                } else if constexpr (EPI == EPI_SCALE) {
                    v *= scale;
                }
                op[(long long)gr * ldo + gc] = f2bf(v);
            }
        }
    }
}

// ======== R11 unified GEMM: 128x128 tile, BK=64, single buffer, 4 blk/CU ==
// (proven: 0 conflicts, MfmaUtil 27%, latency hidden by 4-block co-residency)
template <int EPI>
__global__ __launch_bounds__(256, 4) void gemm(
    const short* __restrict__ A, int lda, long long sAb,
    const short* __restrict__ W, int ldw, long long sWb,
    void* __restrict__ outv, int ldo, long long sOb,
    const float* __restrict__ bias, long long sBias,
    const void* __restrict__ aux,
    int K, float scale, float* __restrict__ lossOut) {
    __shared__ short lds[16384];       // A 8192 + B 8192 shorts = 32 KiB

    const int z = blockIdx.z;
    A += (long long)z * sAb;
    W += (long long)z * sWb;

    const int tid = threadIdx.x;
    const int wid = tid >> 6, lane = tid & 63;
    const int row0 = blockIdx.y * 128, col0 = blockIdx.x * 128;
    const int wrM = (wid >> 1) * 64, wcN = (wid & 1) * 64;
    const int rl = lane & 15, kcl = lane >> 4;

    f32x4 acc[4][4] = {};

    // staging: 8 threads/row (128 B line), source chunk pre-swizzled
    const int srow = tid >> 3;                       // 0..31
    const int cswz = (tid & 7) ^ (srow & 7);
    long long offA[4], offB[4];
#pragma unroll
    for (int j = 0; j < 4; j++) {
        const int rr = j * 32 + srow;                // row&7 == srow&7
        offA[j] = (long long)(row0 + rr) * lda + cswz * 8;
        offB[j] = (long long)(col0 + rr) * ldw + cswz * 8;
    }

    const int nk = K >> 6;
    const int swz0 = (kcl ^ (rl & 7)) * 8;
    const int swz1 = ((kcl + 4) ^ (rl & 7)) * 8;

    for (int t = 0; t < nk; ++t) {
        const short* a = A + (long long)t * 64;
        const short* w = W + (long long)t * 64;
#pragma unroll
        for (int j = 0; j < 4; j++)
            gload16(a + offA[j], lds + (j * 256 + tid) * 8);
#pragma unroll
        for (int j = 0; j < 4; j++)
            gload16(w + offB[j], lds + 8192 + (j * 256 + tid) * 8);
        asm volatile("s_waitcnt vmcnt(0)" ::: "memory");
        __builtin_amdgcn_s_barrier();

        short8 af[4], bfr[4];
        // ---- ks = 0 ----
#pragma unroll
        for (int mi = 0; mi < 4; mi++)
            af[mi] = *(const short8*)&lds[(wrM + mi * 16 + rl) * 64 + swz0];
#pragma unroll
        for (int ni = 0; ni < 4; ni++)
            bfr[ni] = *(const short8*)&lds[8192 + (wcN + ni * 16 + rl) * 64 + swz0];
        __builtin_amdgcn_s_setprio(1);
#pragma unroll
        for (int mi = 0; mi < 4; mi++)
#pragma unroll
            for (int ni = 0; ni < 4; ni++)
                acc[mi][ni] = __builtin_amdgcn_mfma_f32_16x16x32_bf16(
                    af[mi], bfr[ni], acc[mi][ni], 0, 0, 0);
        __builtin_amdgcn_s_setprio(0);
        // ---- ks = 1 ----
#pragma unroll
        for (int mi = 0; mi < 4; mi++)
            af[mi] = *(const short8*)&lds[(wrM + mi * 16 + rl) * 64 + swz1];
#pragma unroll
        for (int ni = 0; ni < 4; ni++)
            bfr[ni] = *(const short8*)&lds[8192 + (wcN + ni * 16 + rl) * 64 + swz1];
        __builtin_amdgcn_s_setprio(1);
#pragma unroll
        for (int mi = 0; mi < 4; mi++)
#pragma unroll
            for (int ni = 0; ni < 4; ni++)
                acc[mi][ni] = __builtin_amdgcn_mfma_f32_16x16x32_bf16(
                    af[mi], bfr[ni], acc[mi][ni], 0, 0, 0);
        __builtin_amdgcn_s_setprio(0);
        __builtin_amdgcn_s_barrier();    // all reads of tile t done before t+1 stages
    }

    // epilogue: C/D layout col=lane&15, row=(lane>>4)*4+r  [m89/m91-verified]
    const int lr4 = (lane >> 4) * 4;
    float bcol[4];
    if constexpr (EPI == EPI_SILU || EPI == EPI_BIAS || EPI == EPI_GATE || EPI == EPI_RESID) {
        const float* bz = bias + (long long)z * sBias;
#pragma unroll
        for (int ni = 0; ni < 4; ni++) bcol[ni] = bz[col0 + wcN + ni * 16 + rl];
    }
    float lsum = 0.f;
#pragma unroll
    for (int mi = 0; mi < 4; mi++) {
#pragma unroll
        for (int ni = 0; ni < 4; ni++) {
            const int gc = col0 + wcN + ni * 16 + rl;
#pragma unroll
            for (int r = 0; r < 4; r++) {
                const int gr = row0 + wrM + mi * 16 + lr4 + r;
                const long long oi = (long long)gr * ldo + gc;
                float v = acc[mi][ni][r];
                if constexpr (EPI == EPI_SILU) {
                    v += bcol[ni];
                    v = v / (1.f + __expf(-v));
                    ((short*)outv + (long long)z * sOb)[oi] = f2bf(v);
                } else if constexpr (EPI == EPI_BIAS) {
                    ((short*)outv + (long long)z * sOb)[oi] = f2bf(v + bcol[ni]);
                } else if constexpr (EPI == EPI_SCALE) {
                    ((short*)outv + (long long)z * sOb)[oi] = f2bf(v * scale);
                } else if constexpr (EPI == EPI_PLAIN) {
                    ((short*)outv + (long long)z * sOb)[oi] = f2bf(v);
                } else if constexpr (EPI == EPI_GATE) {
                    float g = 1.f / (1.f + __expf(-(v + bcol[ni])));
                    float a = bf2f(((const short*)aux)[oi]);
                    ((short*)outv)[oi] = f2bf(g * a);
                } else if constexpr (EPI == EPI_RESID) {
                    ((float*)outv)[oi] = v + bcol[ni] + ((const float*)aux)[oi];
                } else {  // EPI_MLOSS
                    float dd = v - bf2f(((const short*)aux)[oi]);
                    lsum += dd * dd;
                }
            }
        }
    }
    if constexpr (EPI == EPI_MLOSS) {
        lsum = waveSum(lsum);
        if (lane == 0) atomicAdd(lossOut, lsum * scale);
    }
}

// ---------------- host ----------------

extern "C" void kernel_launch(void* const* d_in, const int* in_sizes, int n_in,
                              void* d_out, int out_size, void* d_ws, size_t ws_size,
                              hipStream_t stream) {
    const float* x    = (const float*)d_in[0];
    const float* wq   = (const float*)d_in[1];
    const float* bq   = (const float*)d_in[2];
    const float* wk   = (const float*)d_in[3];
    const float* bk   = (const float*)d_in[4];
    const float* wvw  = (const float*)d_in[5];
    const float* bvv  = (const float*)d_in[6];
    const float* dwq  = (const float*)d_in[7];
    const float* dwqb = (const float*)d_in[8];
    const float* pwq  = (const float*)d_in[9];
    const float* pwqb = (const float*)d_in[10];
    const float* dwk  = (const float*)d_in[11];
    const float* dwkb = (const float*)d_in[12];
    const float* pwk  = (const float*)d_in[13];
    const float* pwkb = (const float*)d_in[14];
    const float* dwv  = (const float*)d_in[15];
    const float* dwvb = (const float*)d_in[16];
    const float* pwv  = (const float*)d_in[17];
    const float* pwvb = (const float*)d_in[18];
    const float* wg   = (const float*)d_in[19];
    const float* bg   = (const float*)d_in[20];
    const float* wo   = (const float*)d_in[21];
    const float* bo   = (const float*)d_in[22];
    const float* memw = (const float*)d_in[23];
    const float* lng  = (const float*)d_in[24];
    const float* lnb  = (const float*)d_in[25];

    float* out = (float*)d_out;
    float* loss = out + BLD;

    char* base = (char*)d_ws;
    size_t off = 0;
    auto take = [&](size_t n) -> char* {
        char* p = base + off;
        off += (n + 255) & ~(size_t)255;
        return p;
    };
    const size_t WB = (size_t)DD * DD * 2;  // 2 MB bf16 weight
    const size_t XB = (size_t)BLD * 2;      // 16.78 MB bf16 activation
    short* Wqkv = (short*)take(3 * WB);     // concat [3072][1024]
    short* Pqkv = (short*)take(3 * WB);     // concat pointwise weights
    short* Wgb  = (short*)take(WB);
    short* Wob  = (short*)take(WB);
    short* MwT  = (short*)take(WB);
    float* bqkv = (float*)take(3072 * 4);
    float* bpw  = (float*)take(3072 * 4);
    short* xb   = (short*)take(XB);         // x bf16; reused as attn_out later
    short* pre  = (short*)take(3 * XB);     // QKV silu [8192][3072]; reused as qb/kb/vb
    short* post = (short*)take(3 * XB);     // conv out [8192][3072]; reused as scores+VT, gated

    short* qb = pre;
    short* kb = pre + BLD;
    short* vb = pre + 2 * BLD;
    short* scores = post;            // [4][2048][2048] bf16 = 2*BLD shorts
    short* VT = post + 2 * BLD;      // [4][1024][2048]
    short* aob = xb;                 // attn_out bf16 (xb dead after QKV GEMM)
    short* gated = post;             // gated bf16 (scores/VT dead after attn@V)
    (void)ws_size; (void)in_sizes; (void)n_in; (void)out_size;

    const long long sLD = (long long)LL * DD;   // 2048*1024
    const long long sLLb = (long long)LL * LL;  // 2048*2048

    k_zero1<<<1, 1, 0, stream>>>(loss);
    k_wcat<<<4096, 256, 0, stream>>>(wq, wk, wvw, pwq, pwk, pwv, wg, wo,
                                     Wqkv, Pqkv, Wgb, Wob);
    k_biascat<<<24, 256, 0, stream>>>(bq, bk, bvv, pwqb, pwkb, pwvb, bqkv, bpw);
    k_transpose_f32_bf16<<<dim3(16, 16, 1), 256, 0, stream>>>(memw, MwT, DD, DD);
    k_f32_to_bf16<<<4096, 256, 0, stream>>>(x, xb, (int)(BLD / 8));

    // fused QKV: silu(x @ [wq;wk;wv]^T + [bq;bk;bv]) -> pre [8192][3072]
    gemm256c<EPI_SILU><<<dim3(24, 32, 1), 256, 0, stream>>>(
        xb, 1024, 0, Wqkv, 1024, 0, pre, 3072, 0, bqkv, 0, 1024, 0.f);

    // fused depthwise conv: pre -> post (8 L-rows per thread, vector weights)
    k_dwconv3b<<<1536, 256, 0, stream>>>(pre, dwq, dwk, dwv, dwqb, dwkb, dwvb, post);

    // batched pointwise: z=3 branches
    gemm256c<EPI_BIAS><<<dim3(8, 32, 3), 256, 0, stream>>>(
        post, 3072, 1024, Pqkv, 1024, (long long)DD * DD, qb, 1024, BLD,
        bpw, 1024, 1024, 0.f);

    // normalize qb AND kb in one launch (contiguous rows of pre) + V^T
    k_l2norm<<<16384, 256, 0, stream>>>(qb);
    k_transpose_bf16<<<dim3(16, 32, 4), 256, 0, stream>>>(vb, VT, 2048, 1024);

    // scores = Qn @ Kn^T / 32  (per batch): 16 x 8 x 4 = 512 blocks
    gemm256c<EPI_SCALE><<<dim3(16, 8, 4), 256, 0, stream>>>(
        qb, 1024, sLD, kb, 1024, sLD, scores, 2048, sLLb,
        nullptr, 0, 1024, 0.03125f);
    k_softmax<<<8192, 256, 0, stream>>>(scores);

    // attn_out = attn @ V  (W = V^T[d, l]) — 128^2 path keeps 4 blk/CU
    gemm<EPI_PLAIN><<<dim3(8, 16, 4), 256, 0, stream>>>(
        scores, 2048, sLLb, VT, 2048, sLD, aob, 1024, sLD,
        nullptr, 0, nullptr, 2048, 0.f, nullptr);

    // gated = sigmoid(attn_out @ wg^T + bg) * attn_out
    gemm<EPI_GATE><<<dim3(8, 64, 1), 256, 0, stream>>>(
        aob, 1024, 0, Wgb, 1024, 0, gated, 1024, 0, bg, 0, aob, 1024, 0.f, nullptr);

    // out = gated @ wo^T + bo + x ; then LN in-place
    gemm<EPI_RESID><<<dim3(8, 64, 1), 256, 0, stream>>>(
        gated, 1024, 0, Wob, 1024, 0, out, 1024, 0, bo, 0, x, 1024, 0.f, nullptr);
    k_layernorm<<<8192, 256, 0, stream>>>(out, lng, lnb);

    // mem_loss = mean((Kn @ mem_w - V)^2)
    gemm<EPI_MLOSS><<<dim3(8, 64, 1), 256, 0, stream>>>(
        kb, 1024, 0, MwT, 1024, 0, nullptr, 1024, 0, nullptr, 0, vb,
        1024, 1.f / (float)BLD, loss);
}

// Round 15
// 379.917 us; speedup vs baseline: 1.1501x; 1.1501x over previous
//
#include <hip/hip_runtime.h>
#include <stdint.h>

typedef __attribute__((ext_vector_type(8))) short short8;
typedef __attribute__((ext_vector_type(4))) short short4v;
typedef __attribute__((ext_vector_type(4))) float f32x4;

#define DEV static __device__ __forceinline__

static constexpr int LL = 2048;
static constexpr int DD = 1024;
static constexpr long long BLD = 8388608LL; // 4*2048*1024
static constexpr long long SLD = 2097152LL;  // 2048*1024
static constexpr long long SLLB = 4194304LL; // 2048*2048

DEV short f2bf(float f) {
    uint32_t u = __builtin_bit_cast(uint32_t, f);
    u += 0x7fffu + ((u >> 16) & 1u);   // RNE
    return (short)(u >> 16);
}
DEV float bf2f(short s) {
    uint32_t u = ((uint32_t)(uint16_t)s) << 16;
    return __builtin_bit_cast(float, u);
}

DEV float waveSum(float v) {
#pragma unroll
    for (int o = 32; o; o >>= 1) v += __shfl_down(v, o);
    return v;
}

DEV void gload16(const void* g, void* l) {
    __builtin_amdgcn_global_load_lds(
        (const __attribute__((address_space(1))) uint32_t*)(uintptr_t)g,
        (__attribute__((address_space(3))) uint32_t*)(uintptr_t)l,
        16, 0, 0);
}

// ---------------- elementwise / reduction kernels ----------------

__global__ __launch_bounds__(256) void k_zero1(float* p) {
    if (threadIdx.x == 0) *p = 0.f;
}

__global__ __launch_bounds__(256) void k_f32_to_bf16(const float* __restrict__ in,
                                                     short* __restrict__ out, int n8) {
    int i = blockIdx.x * 256 + threadIdx.x;
    if (i >= n8) return;
    const float4* p = (const float4*)(in + (long long)i * 8);
    float4 a = p[0], b = p[1];
    short8 o;
    o[0] = f2bf(a.x); o[1] = f2bf(a.y); o[2] = f2bf(a.z); o[3] = f2bf(a.w);
    o[4] = f2bf(b.x); o[5] = f2bf(b.y); o[6] = f2bf(b.z); o[7] = f2bf(b.w);
    *(short8*)(out + (long long)i * 8) = o;
}

// convert 8 D*D fp32 weights to bf16 destinations in one launch (512 blocks each)
__global__ __launch_bounds__(256) void k_wcat(
    const float* wq, const float* wk, const float* wv,
    const float* pq, const float* pk, const float* pv,
    const float* wg, const float* wo,
    short* Wqkv, short* Pqkv, short* Wg, short* Wo) {
    const int bid = blockIdx.x;            // 4096 blocks
    const int w = bid >> 9;                // which weight
    const long long i = (long long)((bid & 511) * 256 + threadIdx.x) * 8;
    const float* src; short* dst;
    switch (w) {
        case 0: src = wq; dst = Wqkv;                break;
        case 1: src = wk; dst = Wqkv + 1048576;      break;
        case 2: src = wv; dst = Wqkv + 2097152;      break;
        case 3: src = pq; dst = Pqkv;                break;
        case 4: src = pk; dst = Pqkv + 1048576;      break;
        case 5: src = pv; dst = Pqkv + 2097152;      break;
        case 6: src = wg; dst = Wg;                  break;
        default: src = wo; dst = Wo;                 break;
    }
    const float4* p = (const float4*)(src + i);
    float4 a = p[0], b = p[1];
    short8 o;
    o[0] = f2bf(a.x); o[1] = f2bf(a.y); o[2] = f2bf(a.z); o[3] = f2bf(a.w);
    o[4] = f2bf(b.x); o[5] = f2bf(b.y); o[6] = f2bf(b.z); o[7] = f2bf(b.w);
    *(short8*)(dst + i) = o;
}

// concat 6 length-1024 fp32 bias vectors into bqkv[3072] and bpw[3072]
__global__ __launch_bounds__(256) void k_biascat(
    const float* bq, const float* bk, const float* bv,
    const float* pq, const float* pk, const float* pv,
    float* bqkv, float* bpw) {
    const int idx = blockIdx.x * 256 + threadIdx.x;  // 24 blocks -> 6144
    const int sel = idx >> 10, j = idx & 1023;
    const float* s;
    switch (sel) {
        case 0: s = bq; break; case 1: s = bk; break; case 2: s = bv; break;
        case 3: s = pq; break; case 4: s = pk; break; default: s = pv; break;
    }
    float v = s[j];
    if (sel < 3) bqkv[sel * 1024 + j] = v;
    else         bpw[(sel - 3) * 1024 + j] = v;
}

// fused depthwise conv over L (k=3, pad 1) + bias, all 3 branches.
__global__ __launch_bounds__(256) void k_dwconv3b(const short* __restrict__ in,
                                                  const float* __restrict__ dwq,
                                                  const float* __restrict__ dwk,
                                                  const float* __restrict__ dwv,
                                                  const float* __restrict__ dbq,
                                                  const float* __restrict__ dbk,
                                                  const float* __restrict__ dbv,
                                                  short* __restrict__ outp) {
    const int idx = blockIdx.x * 256 + threadIdx.x;  // 3*4*256*128 = 393216
    const int d8 = idx & 127;
    const int lc = (idx >> 7) & 255;
    const int b  = (idx >> 15) & 3;
    const int br = idx >> 17;                         // uniform per block
    const float* dw = (br == 0) ? dwq : (br == 1) ? dwk : dwv;
    const float* db = (br == 0) ? dbq : (br == 1) ? dbk : dbv;

    float w[24], bb[8];
    {
        const float4* wp = (const float4*)(dw + d8 * 24);
#pragma unroll
        for (int i = 0; i < 6; i++) {
            float4 t = wp[i];
            w[i * 4 + 0] = t.x; w[i * 4 + 1] = t.y;
            w[i * 4 + 2] = t.z; w[i * 4 + 3] = t.w;
        }
        const float4* bp = (const float4*)(db + d8 * 8);
        float4 t0 = bp[0], t1 = bp[1];
        bb[0] = t0.x; bb[1] = t0.y; bb[2] = t0.z; bb[3] = t0.w;
        bb[4] = t1.x; bb[5] = t1.y; bb[6] = t1.z; bb[7] = t1.w;
    }

    const int l0 = lc * 8;
    const long long base = ((long long)(b * LL + l0)) * 3072 + br * 1024 + d8 * 8;
    short8 xr[10];
#pragma unroll
    for (int i = 0; i < 10; i++) {
        const int l = l0 - 1 + i;
        if (l >= 0 && l < LL) xr[i] = *(const short8*)(in + base + (long long)(i - 1) * 3072);
        else { short8 z = {0, 0, 0, 0, 0, 0, 0, 0}; xr[i] = z; }
    }
#pragma unroll
    for (int j = 0; j < 8; j++) {
        short8 o;
#pragma unroll
        for (int c = 0; c < 8; c++) {
            float v = bb[c] + w[c * 3 + 0] * bf2f(xr[j][c])
                            + w[c * 3 + 1] * bf2f(xr[j + 1][c])
                            + w[c * 3 + 2] * bf2f(xr[j + 2][c]);
            o[c] = f2bf(v);
        }
        *(short8*)(outp + base + (long long)j * 3072) = o;
    }
}

// in-place row L2 normalize, row = blockIdx.x, D=1024, 256 thr * 4
__global__ __launch_bounds__(256) void k_l2norm(short* __restrict__ xp) {
    __shared__ float red[4];
    const long long row = blockIdx.x;
    short* p = xp + row * DD;
    const int t = threadIdx.x;
    short4v v = *(short4v*)(p + t * 4);
    float f0 = bf2f(v[0]), f1 = bf2f(v[1]), f2 = bf2f(v[2]), f3 = bf2f(v[3]);
    float ss = f0 * f0 + f1 * f1 + f2 * f2 + f3 * f3;
    ss = waveSum(ss);
    if ((t & 63) == 0) red[t >> 6] = ss;
    __syncthreads();
    ss = (red[0] + red[1]) + (red[2] + red[3]);
    float s = 1.f / fmaxf(sqrtf(ss), 1e-12f);
    v[0] = f2bf(f0 * s); v[1] = f2bf(f1 * s); v[2] = f2bf(f2 * s); v[3] = f2bf(f3 * s);
    *(short4v*)(p + t * 4) = v;
}

// row sum of P = exp(scores) (bf16, width 2048); writes rinv[row] = 1/sum.
// Replaces the softmax kernel: since |s|<=1/32, exp needs no max-subtraction,
// and attn = P/rowsum applied in the attn@V epilogue (exactly reference math).
__global__ __launch_bounds__(256) void k_rowsuminv(const short* __restrict__ sp,
                                                   float* __restrict__ rinv) {
    __shared__ float red[4];
    const long long row = blockIdx.x;
    const short* p = sp + row * 2048;
    const int t = threadIdx.x;
    short8 v = *(short8*)(p + t * 8);
    float s = 0.f;
#pragma unroll
    for (int j = 0; j < 8; j++) s += bf2f(v[j]);
    s = waveSum(s);
    if ((t & 63) == 0) red[t >> 6] = s;
    __syncthreads();
    s = (red[0] + red[1]) + (red[2] + red[3]);
    if (t == 0) rinv[row] = 1.f / s;
}

// in-place layernorm on fp32 rows of 1024
__global__ __launch_bounds__(256) void k_layernorm(float* __restrict__ y,
                                                   const float* __restrict__ g,
                                                   const float* __restrict__ b) {
    __shared__ float redS[4], redQ[4];
    const long long row = blockIdx.x;
    float* p = y + row * DD;
    const int t = threadIdx.x;
    float4 v = *(float4*)(p + t * 4);
    float s = v.x + v.y + v.z + v.w;
    float q = v.x * v.x + v.y * v.y + v.z * v.z + v.w * v.w;
    s = waveSum(s); q = waveSum(q);
    if ((t & 63) == 0) { redS[t >> 6] = s; redQ[t >> 6] = q; }
    __syncthreads();
    s = (redS[0] + redS[1]) + (redS[2] + redS[3]);
    q = (redQ[0] + redQ[1]) + (redQ[2] + redQ[3]);
    float mu = s * (1.f / DD);
    float var = q * (1.f / DD) - mu * mu;
    float rs = rsqrtf(var + 1e-5f);
    float4 o;
    o.x = (v.x - mu) * rs * g[t * 4 + 0] + b[t * 4 + 0];
    o.y = (v.y - mu) * rs * g[t * 4 + 1] + b[t * 4 + 1];
    o.z = (v.z - mu) * rs * g[t * 4 + 2] + b[t * 4 + 2];
    o.w = (v.w - mu) * rs * g[t * 4 + 3] + b[t * 4 + 3];
    *(float4*)(p + t * 4) = o;
}

// 64x64 LDS-tiled transpose, bf16 -> bf16, per-batch via blockIdx.z
__global__ __launch_bounds__(256) void k_transpose_bf16(const short* __restrict__ in,
                                                        short* __restrict__ out,
                                                        int rows, int cols) {
    __shared__ short tile[64][65];
    const long long boff = (long long)blockIdx.z * rows * cols;
    in += boff; out += boff;
    const int r0 = blockIdx.y * 64, c0 = blockIdx.x * 64;
    const int t = threadIdx.x;
#pragma unroll
    for (int i = 0; i < 16; i++) {
        int lin = i * 256 + t; int lr = lin >> 6, lc = lin & 63;
        tile[lr][lc] = in[(long long)(r0 + lr) * cols + (c0 + lc)];
    }
    __syncthreads();
#pragma unroll
    for (int i = 0; i < 16; i++) {
        int lin = i * 256 + t; int orr = lin >> 6, oc = lin & 63;
        out[(long long)(c0 + orr) * rows + (r0 + oc)] = tile[oc][orr];
    }
}

// 64x64 LDS-tiled transpose, fp32 -> bf16 (for mem_w^T)
__global__ __launch_bounds__(256) void k_transpose_f32_bf16(const float* __restrict__ in,
                                                            short* __restrict__ out,
                                                            int rows, int cols) {
    __shared__ float tile[64][65];
    const int r0 = blockIdx.y * 64, c0 = blockIdx.x * 64;
    const int t = threadIdx.x;
#pragma unroll
    for (int i = 0; i < 16; i++) {
        int lin = i * 256 + t; int lr = lin >> 6, lc = lin & 63;
        tile[lr][lc] = in[(long long)(r0 + lr) * cols + (c0 + lc)];
    }
    __syncthreads();
#pragma unroll
    for (int i = 0; i < 16; i++) {
        int lin = i * 256 + t; int orr = lin >> 6, oc = lin & 63;
        out[(long long)(c0 + orr) * rows + (r0 + oc)] = f2bf(tile[oc][orr]);
    }
}

enum { EPI_SILU, EPI_BIAS, EPI_EXPS, EPI_GATE, EPI_RESID };

// ======== R11 unified GEMM: 128x128 tile, BK=64, single buffer, 4 blk/CU ==
// (R11-proven optimum of this family: 0 conflicts, MfmaUtil 27%, latency
// hidden by 4-block co-residency; 64 acc AGPR + 64 arch = exactly 128 regs.
// R12-R14 established: intensity-raising variants that cut co-residency all
// lose — do not perturb.)  Swizzle: 128 B rows, 8 chunks, chunk c at physical
// c^(row&7); linear gload_lds dest + pre-swizzled global source + same
// involution on ds_read.
template <int EPI>
__global__ __launch_bounds__(256, 4) void gemm(
    const short* __restrict__ A, int lda, long long sAb,
    const short* __restrict__ W, int ldw, long long sWb,
    void* __restrict__ outv, int ldo, long long sOb,
    const float* __restrict__ bias, long long sBias,
    const void* __restrict__ aux,
    int K, float scale) {
    __shared__ short lds[16384];       // A 8192 + B 8192 shorts = 32 KiB

    const int z = blockIdx.z;
    A += (long long)z * sAb;
    W += (long long)z * sWb;

    const int tid = threadIdx.x;
    const int wid = tid >> 6, lane = tid & 63;
    const int row0 = blockIdx.y * 128, col0 = blockIdx.x * 128;
    const int wrM = (wid >> 1) * 64, wcN = (wid & 1) * 64;
    const int rl = lane & 15, kcl = lane >> 4;

    f32x4 acc[4][4] = {};

    const int srow = tid >> 3;                       // 0..31
    const int cswz = (tid & 7) ^ (srow & 7);
    long long offA[4], offB[4];
#pragma unroll
    for (int j = 0; j < 4; j++) {
        const int rr = j * 32 + srow;                // row&7 == srow&7
        offA[j] = (long long)(row0 + rr) * lda + cswz * 8;
        offB[j] = (long long)(col0 + rr) * ldw + cswz * 8;
    }

    const int nk = K >> 6;
    const int swz0 = (kcl ^ (rl & 7)) * 8;
    const int swz1 = ((kcl + 4) ^ (rl & 7)) * 8;

    for (int t = 0; t < nk; ++t) {
        const short* a = A + (long long)t * 64;
        const short* w = W + (long long)t * 64;
#pragma unroll
        for (int j = 0; j < 4; j++)
            gload16(a + offA[j], lds + (j * 256 + tid) * 8);
#pragma unroll
        for (int j = 0; j < 4; j++)
            gload16(w + offB[j], lds + 8192 + (j * 256 + tid) * 8);
        asm volatile("s_waitcnt vmcnt(0)" ::: "memory");
        __builtin_amdgcn_s_barrier();

        short8 af[4], bfr[4];
        // ---- ks = 0 ----
#pragma unroll
        for (int mi = 0; mi < 4; mi++)
            af[mi] = *(const short8*)&lds[(wrM + mi * 16 + rl) * 64 + swz0];
#pragma unroll
        for (int ni = 0; ni < 4; ni++)
            bfr[ni] = *(const short8*)&lds[8192 + (wcN + ni * 16 + rl) * 64 + swz0];
        __builtin_amdgcn_s_setprio(1);
#pragma unroll
        for (int mi = 0; mi < 4; mi++)
#pragma unroll
            for (int ni = 0; ni < 4; ni++)
                acc[mi][ni] = __builtin_amdgcn_mfma_f32_16x16x32_bf16(
                    af[mi], bfr[ni], acc[mi][ni], 0, 0, 0);
        __builtin_amdgcn_s_setprio(0);
        // ---- ks = 1 ----
#pragma unroll
        for (int mi = 0; mi < 4; mi++)
            af[mi] = *(const short8*)&lds[(wrM + mi * 16 + rl) * 64 + swz1];
#pragma unroll
        for (int ni = 0; ni < 4; ni++)
            bfr[ni] = *(const short8*)&lds[8192 + (wcN + ni * 16 + rl) * 64 + swz1];
        __builtin_amdgcn_s_setprio(1);
#pragma unroll
        for (int mi = 0; mi < 4; mi++)
#pragma unroll
            for (int ni = 0; ni < 4; ni++)
                acc[mi][ni] = __builtin_amdgcn_mfma_f32_16x16x32_bf16(
                    af[mi], bfr[ni], acc[mi][ni], 0, 0, 0);
        __builtin_amdgcn_s_setprio(0);
        __builtin_amdgcn_s_barrier();    // all reads of tile t done before t+1 stages
    }

    // epilogue: C/D layout col=lane&15, row=(lane>>4)*4+r  [m89/m91-verified]
    const int lr4 = (lane >> 4) * 4;
    float bcol[4];
    if constexpr (EPI == EPI_SILU || EPI == EPI_BIAS || EPI == EPI_GATE || EPI == EPI_RESID) {
        const float* bz = bias + (long long)z * sBias;
#pragma unroll
        for (int ni = 0; ni < 4; ni++) bcol[ni] = bz[col0 + wcN + ni * 16 + rl];
    }
#pragma unroll
    for (int mi = 0; mi < 4; mi++) {
#pragma unroll
        for (int ni = 0; ni < 4; ni++) {
            const int gc = col0 + wcN + ni * 16 + rl;
#pragma unroll
            for (int r = 0; r < 4; r++) {
                const int gr = row0 + wrM + mi * 16 + lr4 + r;
                const long long oi = (long long)gr * ldo + gc;
                float v = acc[mi][ni][r];
                if constexpr (EPI == EPI_SILU) {
                    v += bcol[ni];
                    v = v / (1.f + __expf(-v));
                    ((short*)outv + (long long)z * sOb)[oi] = f2bf(v);
                } else if constexpr (EPI == EPI_BIAS) {
                    ((short*)outv + (long long)z * sOb)[oi] = f2bf(v + bcol[ni]);
                } else if constexpr (EPI == EPI_EXPS) {
                    // P = exp(s/32); |s|<=1/32 so no max-subtraction needed
                    ((short*)outv + (long long)z * sOb)[oi] = f2bf(__expf(v * scale));
                } else if constexpr (EPI == EPI_GATE) {
                    float g = 1.f / (1.f + __expf(-(v + bcol[ni])));
                    float a = bf2f(((const short*)aux)[oi]);
                    ((short*)outv)[oi] = f2bf(g * a);
                } else if constexpr (EPI == EPI_RESID) {
                    ((float*)outv)[oi] = v + bcol[ni] + ((const float*)aux)[oi];
                }
            }
        }
    }
}

// ======== R15 merged attn@V + mem_loss dispatch (full 4 blk/CU fill) ======
// attn@V (512 blocks) and mem_loss (512 blocks) are independent; separately
// they fill only 2 blk/CU.  One 1024-block dispatch = full co-residency.
// bid<512: attn_out[z] = (P[z] @ VT[z]) * rinv[z][row]   (K=2048)
// bid>=512: mem_loss partial = sum((kb @ MwT - vb)^2)     (K=1024)
// Same R11 loop body; branch is wave-uniform (per-block).
__global__ __launch_bounds__(256, 4) void k_avml(
    const short* __restrict__ P, const short* __restrict__ VT,
    const float* __restrict__ rinv, short* __restrict__ aob,
    const short* __restrict__ kb, const short* __restrict__ MwT,
    const short* __restrict__ vb, float* __restrict__ lossOut) {
    __shared__ short lds[16384];

    const int bid = blockIdx.x;
    const bool isAV = bid < 512;
    const short* A; const short* W;
    int lda, ldw, K, row0, col0;
    const float* rp = nullptr;
    short* outp = nullptr;
    if (isAV) {
        const int z = bid >> 7, rem = bid & 127;
        row0 = (rem >> 3) * 128; col0 = (rem & 7) * 128;
        A = P + (long long)z * SLLB;  lda = 2048;
        W = VT + (long long)z * SLD;  ldw = 2048;
        K = 2048;
        outp = aob + (long long)z * SLD;
        rp = rinv + z * 2048;
    } else {
        const int rem = bid - 512;
        row0 = (rem >> 3) * 128; col0 = (rem & 7) * 128;
        A = kb; lda = 1024; W = MwT; ldw = 1024; K = 1024;
    }

    const int tid = threadIdx.x;
    const int wid = tid >> 6, lane = tid & 63;
    const int wrM = (wid >> 1) * 64, wcN = (wid & 1) * 64;
    const int rl = lane & 15, kcl = lane >> 4;

    f32x4 acc[4][4] = {};

    const int srow = tid >> 3;
    const int cswz = (tid & 7) ^ (srow & 7);
    long long offA[4], offB[4];
#pragma unroll
    for (int j = 0; j < 4; j++) {
        const int rr = j * 32 + srow;
        offA[j] = (long long)(row0 + rr) * lda + cswz * 8;
        offB[j] = (long long)(col0 + rr) * ldw + cswz * 8;
    }

    const int nk = K >> 6;
    const int swz0 = (kcl ^ (rl & 7)) * 8;
    const int swz1 = ((kcl + 4) ^ (rl & 7)) * 8;

    for (int t = 0; t < nk; ++t) {
        const short* a = A + (long long)t * 64;
        const short* w = W + (long long)t * 64;
#pragma unroll
        for (int j = 0; j < 4; j++)
            gload16(a + offA[j], lds + (j * 256 + tid) * 8);
#pragma unroll
        for (int j = 0; j < 4; j++)
            gload16(w + offB[j], lds + 8192 + (j * 256 + tid) * 8);
        asm volatile("s_waitcnt vmcnt(0)" ::: "memory");
        __builtin_amdgcn_s_barrier();

        short8 af[4], bfr[4];
#pragma unroll
        for (int mi = 0; mi < 4; mi++)
            af[mi] = *(const short8*)&lds[(wrM + mi * 16 + rl) * 64 + swz0];
#pragma unroll
        for (int ni = 0; ni < 4; ni++)
            bfr[ni] = *(const short8*)&lds[8192 + (wcN + ni * 16 + rl) * 64 + swz0];
        __builtin_amdgcn_s_setprio(1);
#pragma unroll
        for (int mi = 0; mi < 4; mi++)
#pragma unroll
            for (int ni = 0; ni < 4; ni++)
                acc[mi][ni] = __builtin_amdgcn_mfma_f32_16x16x32_bf16(
                    af[mi], bfr[ni], acc[mi][ni], 0, 0, 0);
        __builtin_amdgcn_s_setprio(0);
#pragma unroll
        for (int mi = 0; mi < 4; mi++)
            af[mi] = *(const short8*)&lds[(wrM + mi * 16 + rl) * 64 + swz1];
#pragma unroll
        for (int ni = 0; ni < 4; ni++)
            bfr[ni] = *(const short8*)&lds[8192 + (wcN + ni * 16 + rl) * 64 + swz1];
        __builtin_amdgcn_s_setprio(1);
#pragma unroll
        for (int mi = 0; mi < 4; mi++)
#pragma unroll
            for (int ni = 0; ni < 4; ni++)
                acc[mi][ni] = __builtin_amdgcn_mfma_f32_16x16x32_bf16(
                    af[mi], bfr[ni], acc[mi][ni], 0, 0, 0);
        __builtin_amdgcn_s_setprio(0);
        __builtin_amdgcn_s_barrier();
    }

    const int lr4 = (lane >> 4) * 4;
    if (isAV) {
#pragma unroll
        for (int mi = 0; mi < 4; mi++) {
#pragma unroll
            for (int ni = 0; ni < 4; ni++) {
                const int gc = col0 + wcN + ni * 16 + rl;
#pragma unroll
                for (int r = 0; r < 4; r++) {
                    const int gr = row0 + wrM + mi * 16 + lr4 + r;
                    outp[(long long)gr * 1024 + gc] = f2bf(acc[mi][ni][r] * rp[gr]);
                }
            }
        }
    } else {
        float lsum = 0.f;
#pragma unroll
        for (int mi = 0; mi < 4; mi++) {
#pragma unroll
            for (int ni = 0; ni < 4; ni++) {
                const int gc = col0 + wcN + ni * 16 + rl;
#pragma unroll
                for (int r = 0; r < 4; r++) {
                    const int gr = row0 + wrM + mi * 16 + lr4 + r;
                    float dd = acc[mi][ni][r] - bf2f(vb[(long long)gr * 1024 + gc]);
                    lsum += dd * dd;
                }
            }
        }
        lsum = waveSum(lsum);
        if (lane == 0) atomicAdd(lossOut, lsum * (1.f / (float)BLD));
    }
}

// ---------------- host ----------------

extern "C" void kernel_launch(void* const* d_in, const int* in_sizes, int n_in,
                              void* d_out, int out_size, void* d_ws, size_t ws_size,
                              hipStream_t stream) {
    const float* x    = (const float*)d_in[0];
    const float* wq   = (const float*)d_in[1];
    const float* bq   = (const float*)d_in[2];
    const float* wk   = (const float*)d_in[3];
    const float* bk   = (const float*)d_in[4];
    const float* wvw  = (const float*)d_in[5];
    const float* bvv  = (const float*)d_in[6];
    const float* dwq  = (const float*)d_in[7];
    const float* dwqb = (const float*)d_in[8];
    const float* pwq  = (const float*)d_in[9];
    const float* pwqb = (const float*)d_in[10];
    const float* dwk  = (const float*)d_in[11];
    const float* dwkb = (const float*)d_in[12];
    const float* pwk  = (const float*)d_in[13];
    const float* pwkb = (const float*)d_in[14];
    const float* dwv  = (const float*)d_in[15];
    const float* dwvb = (const float*)d_in[16];
    const float* pwv  = (const float*)d_in[17];
    const float* pwvb = (const float*)d_in[18];
    const float* wg   = (const float*)d_in[19];
    const float* bg   = (const float*)d_in[20];
    const float* wo   = (const float*)d_in[21];
    const float* bo   = (const float*)d_in[22];
    const float* memw = (const float*)d_in[23];
    const float* lng  = (const float*)d_in[24];
    const float* lnb  = (const float*)d_in[25];

    float* out = (float*)d_out;
    float* loss = out + BLD;

    char* base = (char*)d_ws;
    size_t off = 0;
    auto take = [&](size_t n) -> char* {
        char* p = base + off;
        off += (n + 255) & ~(size_t)255;
        return p;
    };
    const size_t WB = (size_t)DD * DD * 2;  // 2 MB bf16 weight
    const size_t XB = (size_t)BLD * 2;      // 16.78 MB bf16 activation
    short* Wqkv = (short*)take(3 * WB);     // concat [3072][1024]
    short* Pqkv = (short*)take(3 * WB);     // concat pointwise weights
    short* Wgb  = (short*)take(WB);
    short* Wob  = (short*)take(WB);
    short* MwT  = (short*)take(WB);
    float* bqkv = (float*)take(3072 * 4);
    float* bpw  = (float*)take(3072 * 4);
    float* rinv = (float*)take(8192 * 4);   // 1/rowsum of P, [4][2048]
    short* xb   = (short*)take(XB);         // x bf16; reused as attn_out later
    short* pre  = (short*)take(3 * XB);     // QKV silu [8192][3072]; reused as qb/kb/vb
    short* post = (short*)take(3 * XB);     // conv out [8192][3072]; reused as P+VT, gated

    short* qb = pre;
    short* kb = pre + BLD;
    short* vb = pre + 2 * BLD;
    short* scores = post;            // P = exp(s/32): [4][2048][2048] bf16
    short* VT = post + 2 * BLD;      // [4][1024][2048]
    short* aob = xb;                 // attn_out bf16 (xb dead after QKV GEMM)
    short* gated = post;             // gated bf16 (P/VT dead after attn@V)
    (void)ws_size; (void)in_sizes; (void)n_in; (void)out_size;

    const long long sLD = SLD;
    const long long sLLb = SLLB;

    k_zero1<<<1, 1, 0, stream>>>(loss);
    k_wcat<<<4096, 256, 0, stream>>>(wq, wk, wvw, pwq, pwk, pwv, wg, wo,
                                     Wqkv, Pqkv, Wgb, Wob);
    k_biascat<<<24, 256, 0, stream>>>(bq, bk, bvv, pwqb, pwkb, pwvb, bqkv, bpw);
    k_transpose_f32_bf16<<<dim3(16, 16, 1), 256, 0, stream>>>(memw, MwT, DD, DD);
    k_f32_to_bf16<<<4096, 256, 0, stream>>>(x, xb, (int)(BLD / 8));

    // fused QKV: silu(x @ [wq;wk;wv]^T + [bq;bk;bv]) -> pre [8192][3072]
    gemm<EPI_SILU><<<dim3(24, 64, 1), 256, 0, stream>>>(
        xb, 1024, 0, Wqkv, 1024, 0, pre, 3072, 0, bqkv, 0, nullptr, 1024, 0.f);

    // fused depthwise conv: pre -> post
    k_dwconv3b<<<1536, 256, 0, stream>>>(pre, dwq, dwk, dwv, dwqb, dwkb, dwvb, post);

    // batched pointwise: z=3 branches; out -> qb/kb/vb
    gemm<EPI_BIAS><<<dim3(8, 64, 3), 256, 0, stream>>>(
        post, 3072, 1024, Pqkv, 1024, (long long)DD * DD, qb, 1024, BLD,
        bpw, 1024, nullptr, 1024, 0.f);

    // normalize qb AND kb in one launch (contiguous rows of pre) + V^T
    k_l2norm<<<16384, 256, 0, stream>>>(qb);
    k_transpose_bf16<<<dim3(16, 32, 4), 256, 0, stream>>>(vb, VT, 2048, 1024);

    // P = exp(Qn @ Kn^T / 32)  (per batch) — softmax folded into epilogue
    gemm<EPI_EXPS><<<dim3(16, 16, 4), 256, 0, stream>>>(
        qb, 1024, sLD, kb, 1024, sLD, scores, 2048, sLLb,
        nullptr, 0, nullptr, 1024, 0.03125f);
    k_rowsuminv<<<8192, 256, 0, stream>>>(scores, rinv);

    // merged: attn_out = (P @ V) * rinv  AND  mem_loss partials (1024 blocks)
    k_avml<<<1024, 256, 0, stream>>>(scores, VT, rinv, aob, kb, MwT, vb, loss);

    // gated = sigmoid(attn_out @ wg^T + bg) * attn_out
    gemm<EPI_GATE><<<dim3(8, 64, 1), 256, 0, stream>>>(
        aob, 1024, 0, Wgb, 1024, 0, gated, 1024, 0, bg, 0, aob, 1024, 0.f);

    // out = gated @ wo^T + bo + x ; then LN in-place
    gemm<EPI_RESID><<<dim3(8, 64, 1), 256, 0, stream>>>(
        gated, 1024, 0, Wob, 1024, 0, out, 1024, 0, bo, 0, x, 1024, 0.f);
    k_layernorm<<<8192, 256, 0, stream>>>(out, lng, lnb);
}

// Round 16
// 378.989 us; speedup vs baseline: 1.1529x; 1.0024x over previous
//
#include <hip/hip_runtime.h>
#include <stdint.h>

typedef __attribute__((ext_vector_type(8))) short short8;
typedef __attribute__((ext_vector_type(4))) short short4v;
typedef __attribute__((ext_vector_type(4))) float f32x4;

#define DEV static __device__ __forceinline__

static constexpr int LL = 2048;
static constexpr int DD = 1024;
static constexpr long long BLD = 8388608LL; // 4*2048*1024
static constexpr long long SLD = 2097152LL;  // 2048*1024
static constexpr long long SLLB = 4194304LL; // 2048*2048

DEV short f2bf(float f) {
    uint32_t u = __builtin_bit_cast(uint32_t, f);
    u += 0x7fffu + ((u >> 16) & 1u);   // RNE
    return (short)(u >> 16);
}
DEV float bf2f(short s) {
    uint32_t u = ((uint32_t)(uint16_t)s) << 16;
    return __builtin_bit_cast(float, u);
}

DEV float waveSum(float v) {
#pragma unroll
    for (int o = 32; o; o >>= 1) v += __shfl_down(v, o);
    return v;
}

DEV void gload16(const void* g, void* l) {
    __builtin_amdgcn_global_load_lds(
        (const __attribute__((address_space(1))) uint32_t*)(uintptr_t)g,
        (__attribute__((address_space(3))) uint32_t*)(uintptr_t)l,
        16, 0, 0);
}

// ======== R16 k_prep: all independent preprocessing in ONE launch ========
// blocks 0..4095    : 8 weight matrices f32 -> bf16 (wcat)
// blocks 4096..4119 : bias concat (6 x 1024)
// blocks 4120..4375 : mem_w^T f32 -> bf16 (64x64 tiles, 16x16 grid)
// blocks 4376..8471 : x f32 -> bf16
// block  8472       : zero loss scalar
__global__ __launch_bounds__(256) void k_prep(
    const float* __restrict__ x,
    const float* wq, const float* wk, const float* wv,
    const float* pq, const float* pk, const float* pv,
    const float* wg, const float* wo,
    const float* bq, const float* bk, const float* bv,
    const float* pqb, const float* pkb, const float* pvb,
    const float* __restrict__ memw,
    short* Wqkv, short* Pqkv, short* Wg, short* Wo,
    float* bqkv, float* bpw, short* MwT, short* xb, float* loss) {
    __shared__ float tile[64][65];
    const int bid = blockIdx.x;
    const int t = threadIdx.x;

    if (bid < 4096) {
        const int w = bid >> 9;
        const long long i = (long long)((bid & 511) * 256 + t) * 8;
        const float* src; short* dst;
        switch (w) {
            case 0: src = wq; dst = Wqkv;                break;
            case 1: src = wk; dst = Wqkv + 1048576;      break;
            case 2: src = wv; dst = Wqkv + 2097152;      break;
            case 3: src = pq; dst = Pqkv;                break;
            case 4: src = pk; dst = Pqkv + 1048576;      break;
            case 5: src = pv; dst = Pqkv + 2097152;      break;
            case 6: src = wg; dst = Wg;                  break;
            default: src = wo; dst = Wo;                 break;
        }
        const float4* p = (const float4*)(src + i);
        float4 a = p[0], b = p[1];
        short8 o;
        o[0] = f2bf(a.x); o[1] = f2bf(a.y); o[2] = f2bf(a.z); o[3] = f2bf(a.w);
        o[4] = f2bf(b.x); o[5] = f2bf(b.y); o[6] = f2bf(b.z); o[7] = f2bf(b.w);
        *(short8*)(dst + i) = o;
    } else if (bid < 4120) {
        const int idx = (bid - 4096) * 256 + t;  // 6144
        const int sel = idx >> 10, j = idx & 1023;
        const float* s;
        switch (sel) {
            case 0: s = bq; break; case 1: s = bk; break; case 2: s = bv; break;
            case 3: s = pqb; break; case 4: s = pkb; break; default: s = pvb; break;
        }
        float v = s[j];
        if (sel < 3) bqkv[sel * 1024 + j] = v;
        else         bpw[(sel - 3) * 1024 + j] = v;
    } else if (bid < 4376) {
        const int tt = bid - 4120;               // 0..255 -> 16x16 tiles
        const int r0 = (tt >> 4) * 64, c0 = (tt & 15) * 64;
#pragma unroll
        for (int i = 0; i < 16; i++) {
            int lin = i * 256 + t; int lr = lin >> 6, lc = lin & 63;
            tile[lr][lc] = memw[(long long)(r0 + lr) * DD + (c0 + lc)];
        }
        __syncthreads();
#pragma unroll
        for (int i = 0; i < 16; i++) {
            int lin = i * 256 + t; int orr = lin >> 6, oc = lin & 63;
            MwT[(long long)(c0 + orr) * DD + (r0 + oc)] = f2bf(tile[oc][orr]);
        }
    } else if (bid < 8472) {
        const long long i = (long long)((bid - 4376) * 256 + t) * 8;
        const float4* p = (const float4*)(x + i);
        float4 a = p[0], b = p[1];
        short8 o;
        o[0] = f2bf(a.x); o[1] = f2bf(a.y); o[2] = f2bf(a.z); o[3] = f2bf(a.w);
        o[4] = f2bf(b.x); o[5] = f2bf(b.y); o[6] = f2bf(b.z); o[7] = f2bf(b.w);
        *(short8*)(xb + i) = o;
    } else {
        if (t == 0) *loss = 0.f;
    }
}

// fused depthwise conv over L (k=3, pad 1) + bias, all 3 branches.
__global__ __launch_bounds__(256) void k_dwconv3b(const short* __restrict__ in,
                                                  const float* __restrict__ dwq,
                                                  const float* __restrict__ dwk,
                                                  const float* __restrict__ dwv,
                                                  const float* __restrict__ dbq,
                                                  const float* __restrict__ dbk,
                                                  const float* __restrict__ dbv,
                                                  short* __restrict__ outp) {
    const int idx = blockIdx.x * 256 + threadIdx.x;  // 3*4*256*128 = 393216
    const int d8 = idx & 127;
    const int lc = (idx >> 7) & 255;
    const int b  = (idx >> 15) & 3;
    const int br = idx >> 17;                         // uniform per block
    const float* dw = (br == 0) ? dwq : (br == 1) ? dwk : dwv;
    const float* db = (br == 0) ? dbq : (br == 1) ? dbk : dbv;

    float w[24], bb[8];
    {
        const float4* wp = (const float4*)(dw + d8 * 24);
#pragma unroll
        for (int i = 0; i < 6; i++) {
            float4 tt = wp[i];
            w[i * 4 + 0] = tt.x; w[i * 4 + 1] = tt.y;
            w[i * 4 + 2] = tt.z; w[i * 4 + 3] = tt.w;
        }
        const float4* bp = (const float4*)(db + d8 * 8);
        float4 t0 = bp[0], t1 = bp[1];
        bb[0] = t0.x; bb[1] = t0.y; bb[2] = t0.z; bb[3] = t0.w;
        bb[4] = t1.x; bb[5] = t1.y; bb[6] = t1.z; bb[7] = t1.w;
    }

    const int l0 = lc * 8;
    const long long base = ((long long)(b * LL + l0)) * 3072 + br * 1024 + d8 * 8;
    short8 xr[10];
#pragma unroll
    for (int i = 0; i < 10; i++) {
        const int l = l0 - 1 + i;
        if (l >= 0 && l < LL) xr[i] = *(const short8*)(in + base + (long long)(i - 1) * 3072);
        else { short8 z = {0, 0, 0, 0, 0, 0, 0, 0}; xr[i] = z; }
    }
#pragma unroll
    for (int j = 0; j < 8; j++) {
        short8 o;
#pragma unroll
        for (int c = 0; c < 8; c++) {
            float v = bb[c] + w[c * 3 + 0] * bf2f(xr[j][c])
                            + w[c * 3 + 1] * bf2f(xr[j + 1][c])
                            + w[c * 3 + 2] * bf2f(xr[j + 2][c]);
            o[c] = f2bf(v);
        }
        *(short8*)(outp + base + (long long)j * 3072) = o;
    }
}

// ======== R16 k_vt_norm: V^T transpose + Q/K inverse row norms, one launch
// blocks 0..2047     : 64x64 bf16 transpose tiles of vb -> VT (per batch)
// blocks 2048..18431 : row = bid-2048 of pre[16384][1024] (qb rows 0..8191,
//                      kb rows 8192..16383); ninv[row] = 1/max(|row|,1e-12)
__global__ __launch_bounds__(256) void k_vt_norm(const short* __restrict__ vb,
                                                 short* __restrict__ VT,
                                                 const short* __restrict__ qkb,
                                                 float* __restrict__ ninv) {
    __shared__ short tile[64][65];
    __shared__ float red[4];
    const int bid = blockIdx.x;
    const int t = threadIdx.x;
    if (bid < 2048) {
        const int z = bid >> 9, tt = bid & 511;
        const int r0 = (tt >> 4) * 64, c0 = (tt & 15) * 64;
        const short* in = vb + (long long)z * SLD;
        short* out = VT + (long long)z * SLD;
#pragma unroll
        for (int i = 0; i < 16; i++) {
            int lin = i * 256 + t; int lr = lin >> 6, lc = lin & 63;
            tile[lr][lc] = in[(long long)(r0 + lr) * 1024 + (c0 + lc)];
        }
        __syncthreads();
#pragma unroll
        for (int i = 0; i < 16; i++) {
            int lin = i * 256 + t; int orr = lin >> 6, oc = lin & 63;
            out[(long long)(c0 + orr) * 2048 + (r0 + oc)] = tile[oc][orr];
        }
    } else {
        const long long row = bid - 2048;
        const short* p = qkb + row * DD;
        short4v v = *(const short4v*)(p + t * 4);
        float f0 = bf2f(v[0]), f1 = bf2f(v[1]), f2 = bf2f(v[2]), f3 = bf2f(v[3]);
        float ss = f0 * f0 + f1 * f1 + f2 * f2 + f3 * f3;
        ss = waveSum(ss);
        if ((t & 63) == 0) red[t >> 6] = ss;
        __syncthreads();
        ss = (red[0] + red[1]) + (red[2] + red[3]);
        if (t == 0) ninv[row] = 1.f / fmaxf(sqrtf(ss), 1e-12f);
    }
}

// row sum of P = exp(scores) (bf16, width 2048); writes rinv[row] = 1/sum.
__global__ __launch_bounds__(256) void k_rowsuminv(const short* __restrict__ sp,
                                                   float* __restrict__ rinv) {
    __shared__ float red[4];
    const long long row = blockIdx.x;
    const short* p = sp + row * 2048;
    const int t = threadIdx.x;
    short8 v = *(short8*)(p + t * 8);
    float s = 0.f;
#pragma unroll
    for (int j = 0; j < 8; j++) s += bf2f(v[j]);
    s = waveSum(s);
    if ((t & 63) == 0) red[t >> 6] = s;
    __syncthreads();
    s = (red[0] + red[1]) + (red[2] + red[3]);
    if (t == 0) rinv[row] = 1.f / s;
}

// in-place layernorm on fp32 rows of 1024
__global__ __launch_bounds__(256) void k_layernorm(float* __restrict__ y,
                                                   const float* __restrict__ g,
                                                   const float* __restrict__ b) {
    __shared__ float redS[4], redQ[4];
    const long long row = blockIdx.x;
    float* p = y + row * DD;
    const int t = threadIdx.x;
    float4 v = *(float4*)(p + t * 4);
    float s = v.x + v.y + v.z + v.w;
    float q = v.x * v.x + v.y * v.y + v.z * v.z + v.w * v.w;
    s = waveSum(s); q = waveSum(q);
    if ((t & 63) == 0) { redS[t >> 6] = s; redQ[t >> 6] = q; }
    __syncthreads();
    s = (redS[0] + redS[1]) + (redS[2] + redS[3]);
    q = (redQ[0] + redQ[1]) + (redQ[2] + redQ[3]);
    float mu = s * (1.f / DD);
    float var = q * (1.f / DD) - mu * mu;
    float rs = rsqrtf(var + 1e-5f);
    float4 o;
    o.x = (v.x - mu) * rs * g[t * 4 + 0] + b[t * 4 + 0];
    o.y = (v.y - mu) * rs * g[t * 4 + 1] + b[t * 4 + 1];
    o.z = (v.z - mu) * rs * g[t * 4 + 2] + b[t * 4 + 2];
    o.w = (v.w - mu) * rs * g[t * 4 + 3] + b[t * 4 + 3];
    *(float4*)(p + t * 4) = o;
}

enum { EPI_SILU, EPI_BIAS, EPI_EXPS, EPI_GATE, EPI_RESID };

// ======== R11 unified GEMM: 128x128 tile, BK=64, single buffer, 4 blk/CU ==
// (proven optimum of this family; R12-R14: do not perturb.)
// EPI_EXPS (R16): P = exp((A@W^T)[r,c] * qinv[r] * kinv[c] / 32) — l2norm
// folded in fp32 (bias arg = qinv base, aux = kinv base, both +z*2048).
template <int EPI>
__global__ __launch_bounds__(256, 4) void gemm(
    const short* __restrict__ A, int lda, long long sAb,
    const short* __restrict__ W, int ldw, long long sWb,
    void* __restrict__ outv, int ldo, long long sOb,
    const float* __restrict__ bias, long long sBias,
    const void* __restrict__ aux,
    int K, float scale) {
    __shared__ short lds[16384];       // A 8192 + B 8192 shorts = 32 KiB

    const int z = blockIdx.z;
    A += (long long)z * sAb;
    W += (long long)z * sWb;

    const int tid = threadIdx.x;
    const int wid = tid >> 6, lane = tid & 63;
    const int row0 = blockIdx.y * 128, col0 = blockIdx.x * 128;
    const int wrM = (wid >> 1) * 64, wcN = (wid & 1) * 64;
    const int rl = lane & 15, kcl = lane >> 4;

    f32x4 acc[4][4] = {};

    const int srow = tid >> 3;                       // 0..31
    const int cswz = (tid & 7) ^ (srow & 7);
    long long offA[4], offB[4];
#pragma unroll
    for (int j = 0; j < 4; j++) {
        const int rr = j * 32 + srow;                // row&7 == srow&7
        offA[j] = (long long)(row0 + rr) * lda + cswz * 8;
        offB[j] = (long long)(col0 + rr) * ldw + cswz * 8;
    }

    const int nk = K >> 6;
    const int swz0 = (kcl ^ (rl & 7)) * 8;
    const int swz1 = ((kcl + 4) ^ (rl & 7)) * 8;

    for (int t = 0; t < nk; ++t) {
        const short* a = A + (long long)t * 64;
        const short* w = W + (long long)t * 64;
#pragma unroll
        for (int j = 0; j < 4; j++)
            gload16(a + offA[j], lds + (j * 256 + tid) * 8);
#pragma unroll
        for (int j = 0; j < 4; j++)
            gload16(w + offB[j], lds + 8192 + (j * 256 + tid) * 8);
        asm volatile("s_waitcnt vmcnt(0)" ::: "memory");
        __builtin_amdgcn_s_barrier();

        short8 af[4], bfr[4];
#pragma unroll
        for (int mi = 0; mi < 4; mi++)
            af[mi] = *(const short8*)&lds[(wrM + mi * 16 + rl) * 64 + swz0];
#pragma unroll
        for (int ni = 0; ni < 4; ni++)
            bfr[ni] = *(const short8*)&lds[8192 + (wcN + ni * 16 + rl) * 64 + swz0];
        __builtin_amdgcn_s_setprio(1);
#pragma unroll
        for (int mi = 0; mi < 4; mi++)
#pragma unroll
            for (int ni = 0; ni < 4; ni++)
                acc[mi][ni] = __builtin_amdgcn_mfma_f32_16x16x32_bf16(
                    af[mi], bfr[ni], acc[mi][ni], 0, 0, 0);
        __builtin_amdgcn_s_setprio(0);
#pragma unroll
        for (int mi = 0; mi < 4; mi++)
            af[mi] = *(const short8*)&lds[(wrM + mi * 16 + rl) * 64 + swz1];
#pragma unroll
        for (int ni = 0; ni < 4; ni++)
            bfr[ni] = *(const short8*)&lds[8192 + (wcN + ni * 16 + rl) * 64 + swz1];
        __builtin_amdgcn_s_setprio(1);
#pragma unroll
        for (int mi = 0; mi < 4; mi++)
#pragma unroll
            for (int ni = 0; ni < 4; ni++)
                acc[mi][ni] = __builtin_amdgcn_mfma_f32_16x16x32_bf16(
                    af[mi], bfr[ni], acc[mi][ni], 0, 0, 0);
        __builtin_amdgcn_s_setprio(0);
        __builtin_amdgcn_s_barrier();    // all reads of tile t done before t+1 stages
    }

    // epilogue: C/D layout col=lane&15, row=(lane>>4)*4+r  [m89/m91-verified]
    const int lr4 = (lane >> 4) * 4;
    float bcol[4];
    if constexpr (EPI == EPI_SILU || EPI == EPI_BIAS || EPI == EPI_GATE || EPI == EPI_RESID) {
        const float* bz = bias + (long long)z * sBias;
#pragma unroll
        for (int ni = 0; ni < 4; ni++) bcol[ni] = bz[col0 + wcN + ni * 16 + rl];
    }
    if constexpr (EPI == EPI_EXPS) {
        const float* kz = (const float*)aux + (long long)z * 2048;
#pragma unroll
        for (int ni = 0; ni < 4; ni++) bcol[ni] = kz[col0 + wcN + ni * 16 + rl];
    }
    const float* qz = (EPI == EPI_EXPS) ? bias + (long long)z * sBias : nullptr;
#pragma unroll
    for (int mi = 0; mi < 4; mi++) {
#pragma unroll
        for (int ni = 0; ni < 4; ni++) {
            const int gc = col0 + wcN + ni * 16 + rl;
#pragma unroll
            for (int r = 0; r < 4; r++) {
                const int gr = row0 + wrM + mi * 16 + lr4 + r;
                const long long oi = (long long)gr * ldo + gc;
                float v = acc[mi][ni][r];
                if constexpr (EPI == EPI_SILU) {
                    v += bcol[ni];
                    v = v / (1.f + __expf(-v));
                    ((short*)outv + (long long)z * sOb)[oi] = f2bf(v);
                } else if constexpr (EPI == EPI_BIAS) {
                    ((short*)outv + (long long)z * sOb)[oi] = f2bf(v + bcol[ni]);
                } else if constexpr (EPI == EPI_EXPS) {
                    // P = exp(cos/32); |cos|<=~1 so no max-subtraction needed
                    ((short*)outv + (long long)z * sOb)[oi] =
                        f2bf(__expf(v * qz[gr] * bcol[ni] * scale));
                } else if constexpr (EPI == EPI_GATE) {
                    float g = 1.f / (1.f + __expf(-(v + bcol[ni])));
                    float a = bf2f(((const short*)aux)[oi]);
                    ((short*)outv)[oi] = f2bf(g * a);
                } else if constexpr (EPI == EPI_RESID) {
                    ((float*)outv)[oi] = v + bcol[ni] + ((const float*)aux)[oi];
                }
            }
        }
    }
}

// ======== merged attn@V + mem_loss dispatch (full 4 blk/CU fill) ======
// bid<512: attn_out[z] = (P[z] @ VT[z]) * rinv[z][row]          (K=2048)
// bid>=512: mem_loss partial = sum(((kb@MwT)*kinv[row] - vb)^2) (K=1024)
__global__ __launch_bounds__(256, 4) void k_avml(
    const short* __restrict__ P, const short* __restrict__ VT,
    const float* __restrict__ rinv, short* __restrict__ aob,
    const short* __restrict__ kb, const short* __restrict__ MwT,
    const short* __restrict__ vb, const float* __restrict__ kinv,
    float* __restrict__ lossOut) {
    __shared__ short lds[16384];

    const int bid = blockIdx.x;
    const bool isAV = bid < 512;
    const short* A; const short* W;
    int lda, ldw, K, row0, col0;
    const float* rp = nullptr;
    short* outp = nullptr;
    if (isAV) {
        const int z = bid >> 7, rem = bid & 127;
        row0 = (rem >> 3) * 128; col0 = (rem & 7) * 128;
        A = P + (long long)z * SLLB;  lda = 2048;
        W = VT + (long long)z * SLD;  ldw = 2048;
        K = 2048;
        outp = aob + (long long)z * SLD;
        rp = rinv + z * 2048;
    } else {
        const int rem = bid - 512;
        row0 = (rem >> 3) * 128; col0 = (rem & 7) * 128;
        A = kb; lda = 1024; W = MwT; ldw = 1024; K = 1024;
    }

    const int tid = threadIdx.x;
    const int wid = tid >> 6, lane = tid & 63;
    const int wrM = (wid >> 1) * 64, wcN = (wid & 1) * 64;
    const int rl = lane & 15, kcl = lane >> 4;

    f32x4 acc[4][4] = {};

    const int srow = tid >> 3;
    const int cswz = (tid & 7) ^ (srow & 7);
    long long offA[4], offB[4];
#pragma unroll
    for (int j = 0; j < 4; j++) {
        const int rr = j * 32 + srow;
        offA[j] = (long long)(row0 + rr) * lda + cswz * 8;
        offB[j] = (long long)(col0 + rr) * ldw + cswz * 8;
    }

    const int nk = K >> 6;
    const int swz0 = (kcl ^ (rl & 7)) * 8;
    const int swz1 = ((kcl + 4) ^ (rl & 7)) * 8;

    for (int t = 0; t < nk; ++t) {
        const short* a = A + (long long)t * 64;
        const short* w = W + (long long)t * 64;
#pragma unroll
        for (int j = 0; j < 4; j++)
            gload16(a + offA[j], lds + (j * 256 + tid) * 8);
#pragma unroll
        for (int j = 0; j < 4; j++)
            gload16(w + offB[j], lds + 8192 + (j * 256 + tid) * 8);
        asm volatile("s_waitcnt vmcnt(0)" ::: "memory");
        __builtin_amdgcn_s_barrier();

        short8 af[4], bfr[4];
#pragma unroll
        for (int mi = 0; mi < 4; mi++)
            af[mi] = *(const short8*)&lds[(wrM + mi * 16 + rl) * 64 + swz0];
#pragma unroll
        for (int ni = 0; ni < 4; ni++)
            bfr[ni] = *(const short8*)&lds[8192 + (wcN + ni * 16 + rl) * 64 + swz0];
        __builtin_amdgcn_s_setprio(1);
#pragma unroll
        for (int mi = 0; mi < 4; mi++)
#pragma unroll
            for (int ni = 0; ni < 4; ni++)
                acc[mi][ni] = __builtin_amdgcn_mfma_f32_16x16x32_bf16(
                    af[mi], bfr[ni], acc[mi][ni], 0, 0, 0);
        __builtin_amdgcn_s_setprio(0);
#pragma unroll
        for (int mi = 0; mi < 4; mi++)
            af[mi] = *(const short8*)&lds[(wrM + mi * 16 + rl) * 64 + swz1];
#pragma unroll
        for (int ni = 0; ni < 4; ni++)
            bfr[ni] = *(const short8*)&lds[8192 + (wcN + ni * 16 + rl) * 64 + swz1];
        __builtin_amdgcn_s_setprio(1);
#pragma unroll
        for (int mi = 0; mi < 4; mi++)
#pragma unroll
            for (int ni = 0; ni < 4; ni++)
                acc[mi][ni] = __builtin_amdgcn_mfma_f32_16x16x32_bf16(
                    af[mi], bfr[ni], acc[mi][ni], 0, 0, 0);
        __builtin_amdgcn_s_setprio(0);
        __builtin_amdgcn_s_barrier();
    }

    const int lr4 = (lane >> 4) * 4;
    if (isAV) {
#pragma unroll
        for (int mi = 0; mi < 4; mi++) {
#pragma unroll
            for (int ni = 0; ni < 4; ni++) {
                const int gc = col0 + wcN + ni * 16 + rl;
#pragma unroll
                for (int r = 0; r < 4; r++) {
                    const int gr = row0 + wrM + mi * 16 + lr4 + r;
                    outp[(long long)gr * 1024 + gc] = f2bf(acc[mi][ni][r] * rp[gr]);
                }
            }
        }
    } else {
        float lsum = 0.f;
#pragma unroll
        for (int mi = 0; mi < 4; mi++) {
#pragma unroll
            for (int ni = 0; ni < 4; ni++) {
                const int gc = col0 + wcN + ni * 16 + rl;
#pragma unroll
                for (int r = 0; r < 4; r++) {
                    const int gr = row0 + wrM + mi * 16 + lr4 + r;
                    float dd = acc[mi][ni][r] * kinv[gr] - bf2f(vb[(long long)gr * 1024 + gc]);
                    lsum += dd * dd;
                }
            }
        }
        lsum = waveSum(lsum);
        if (lane == 0) atomicAdd(lossOut, lsum * (1.f / (float)BLD));
    }
}

// ---------------- host ----------------

extern "C" void kernel_launch(void* const* d_in, const int* in_sizes, int n_in,
                              void* d_out, int out_size, void* d_ws, size_t ws_size,
                              hipStream_t stream) {
    const float* x    = (const float*)d_in[0];
    const float* wq   = (const float*)d_in[1];
    const float* bq   = (const float*)d_in[2];
    const float* wk   = (const float*)d_in[3];
    const float* bk   = (const float*)d_in[4];
    const float* wvw  = (const float*)d_in[5];
    const float* bvv  = (const float*)d_in[6];
    const float* dwq  = (const float*)d_in[7];
    const float* dwqb = (const float*)d_in[8];
    const float* pwq  = (const float*)d_in[9];
    const float* pwqb = (const float*)d_in[10];
    const float* dwk  = (const float*)d_in[11];
    const float* dwkb = (const float*)d_in[12];
    const float* pwk  = (const float*)d_in[13];
    const float* pwkb = (const float*)d_in[14];
    const float* dwv  = (const float*)d_in[15];
    const float* dwvb = (const float*)d_in[16];
    const float* pwv  = (const float*)d_in[17];
    const float* pwvb = (const float*)d_in[18];
    const float* wg   = (const float*)d_in[19];
    const float* bg   = (const float*)d_in[20];
    const float* wo   = (const float*)d_in[21];
    const float* bo   = (const float*)d_in[22];
    const float* memw = (const float*)d_in[23];
    const float* lng  = (const float*)d_in[24];
    const float* lnb  = (const float*)d_in[25];

    float* out = (float*)d_out;
    float* loss = out + BLD;

    char* base = (char*)d_ws;
    size_t off = 0;
    auto take = [&](size_t n) -> char* {
        char* p = base + off;
        off += (n + 255) & ~(size_t)255;
        return p;
    };
    const size_t WB = (size_t)DD * DD * 2;  // 2 MB bf16 weight
    const size_t XB = (size_t)BLD * 2;      // 16.78 MB bf16 activation
    short* Wqkv = (short*)take(3 * WB);     // concat [3072][1024]
    short* Pqkv = (short*)take(3 * WB);     // concat pointwise weights
    short* Wgb  = (short*)take(WB);
    short* Wob  = (short*)take(WB);
    short* MwT  = (short*)take(WB);
    float* bqkv = (float*)take(3072 * 4);
    float* bpw  = (float*)take(3072 * 4);
    float* rinv = (float*)take(8192 * 4);   // 1/rowsum of P, [4][2048]
    float* ninv = (float*)take(16384 * 4);  // 1/|row|: qinv [8192], kinv [8192]
    short* xb   = (short*)take(XB);         // x bf16; reused as attn_out later
    short* pre  = (short*)take(3 * XB);     // QKV silu [8192][3072]; reused as qb/kb/vb
    short* post = (short*)take(3 * XB);     // conv out [8192][3072]; reused as P+VT, gated

    short* qb = pre;
    short* kb = pre + BLD;
    short* vb = pre + 2 * BLD;
    short* scores = post;            // P = exp(cos/32): [4][2048][2048] bf16
    short* VT = post + 2 * BLD;      // [4][1024][2048]
    short* aob = xb;                 // attn_out bf16 (xb dead after QKV GEMM)
    short* gated = post;             // gated bf16 (P/VT dead after attn@V)
    float* qinv = ninv;
    float* kinv = ninv + 8192;
    (void)ws_size; (void)in_sizes; (void)n_in; (void)out_size;

    const long long sLD = SLD;
    const long long sLLb = SLLB;

    // all preprocessing in one launch
    k_prep<<<8473, 256, 0, stream>>>(
        x, wq, wk, wvw, pwq, pwk, pwv, wg, wo,
        bq, bk, bvv, pwqb, pwkb, pwvb, memw,
        Wqkv, Pqkv, Wgb, Wob, bqkv, bpw, MwT, xb, loss);

    // fused QKV: silu(x @ [wq;wk;wv]^T + [bq;bk;bv]) -> pre [8192][3072]
    gemm<EPI_SILU><<<dim3(24, 64, 1), 256, 0, stream>>>(
        xb, 1024, 0, Wqkv, 1024, 0, pre, 3072, 0, bqkv, 0, nullptr, 1024, 0.f);

    // fused depthwise conv: pre -> post
    k_dwconv3b<<<1536, 256, 0, stream>>>(pre, dwq, dwk, dwv, dwqb, dwkb, dwvb, post);

    // batched pointwise: z=3 branches; out -> qb/kb/vb
    gemm<EPI_BIAS><<<dim3(8, 64, 3), 256, 0, stream>>>(
        post, 3072, 1024, Pqkv, 1024, (long long)DD * DD, qb, 1024, BLD,
        bpw, 1024, nullptr, 1024, 0.f);

    // V^T transpose + Q/K inverse row norms in one launch
    k_vt_norm<<<18432, 256, 0, stream>>>(vb, VT, qb, ninv);

    // P = exp((Q@K^T) * qinv * kinv / 32)  — l2norm + softmax-exp folded
    gemm<EPI_EXPS><<<dim3(16, 16, 4), 256, 0, stream>>>(
        qb, 1024, sLD, kb, 1024, sLD, scores, 2048, sLLb,
        qinv, 2048, kinv, 1024, 0.03125f);
    k_rowsuminv<<<8192, 256, 0, stream>>>(scores, rinv);

    // merged: attn_out = (P @ V) * rinv  AND  mem_loss partials (1024 blocks)
    k_avml<<<1024, 256, 0, stream>>>(scores, VT, rinv, aob, kb, MwT, vb, kinv, loss);

    // gated = sigmoid(attn_out @ wg^T + bg) * attn_out
    gemm<EPI_GATE><<<dim3(8, 64, 1), 256, 0, stream>>>(
        aob, 1024, 0, Wgb, 1024, 0, gated, 1024, 0, bg, 0, aob, 1024, 0.f);

    // out = gated @ wo^T + bo + x ; then LN in-place
    gemm<EPI_RESID><<<dim3(8, 64, 1), 256, 0, stream>>>(
        gated, 1024, 0, Wob, 1024, 0, out, 1024, 0, bo, 0, x, 1024, 0.f);
    k_layernorm<<<8192, 256, 0, stream>>>(out, lng, lnb);
}

// Round 17
// 345.027 us; speedup vs baseline: 1.2664x; 1.0984x over previous
//
#include <hip/hip_runtime.h>
#include <stdint.h>

typedef __attribute__((ext_vector_type(8))) short short8;
typedef __attribute__((ext_vector_type(4))) short short4v;
typedef __attribute__((ext_vector_type(4))) float f32x4;

#define DEV static __device__ __forceinline__

static constexpr int LL = 2048;
static constexpr int DD = 1024;
static constexpr long long BLD = 8388608LL; // 4*2048*1024
static constexpr long long SLD = 2097152LL;  // 2048*1024
static constexpr long long SLLB = 4194304LL; // 2048*2048

DEV short f2bf(float f) {
    uint32_t u = __builtin_bit_cast(uint32_t, f);
    u += 0x7fffu + ((u >> 16) & 1u);   // RNE
    return (short)(u >> 16);
}
DEV float bf2f(short s) {
    uint32_t u = ((uint32_t)(uint16_t)s) << 16;
    return __builtin_bit_cast(float, u);
}

DEV float waveSum(float v) {
#pragma unroll
    for (int o = 32; o; o >>= 1) v += __shfl_down(v, o);
    return v;
}

DEV void gload16(const void* g, void* l) {
    __builtin_amdgcn_global_load_lds(
        (const __attribute__((address_space(1))) uint32_t*)(uintptr_t)g,
        (__attribute__((address_space(3))) uint32_t*)(uintptr_t)l,
        16, 0, 0);
}

// ======== k_prep: all independent preprocessing in ONE launch ========
// blocks 0..4095    : 8 weight matrices f32 -> bf16
// blocks 4096..4119 : bias concat (6 x 1024)
// blocks 4120..4375 : mem_w^T f32 -> bf16 (64x64 tiles)
// blocks 4376..8471 : x f32 -> bf16
// block  8472       : zero loss scalar
// blocks 8473..8504 : zero rsum[8192]
__global__ __launch_bounds__(256) void k_prep(
    const float* __restrict__ x,
    const float* wq, const float* wk, const float* wv,
    const float* pq, const float* pk, const float* pv,
    const float* wg, const float* wo,
    const float* bq, const float* bk, const float* bv,
    const float* pqb, const float* pkb, const float* pvb,
    const float* __restrict__ memw,
    short* Wqkv, short* Pqkv, short* Wg, short* Wo,
    float* bqkv, float* bpw, short* MwT, short* xb, float* loss,
    float* rsum) {
    __shared__ float tile[64][65];
    const int bid = blockIdx.x;
    const int t = threadIdx.x;

    if (bid < 4096) {
        const int w = bid >> 9;
        const long long i = (long long)((bid & 511) * 256 + t) * 8;
        const float* src; short* dst;
        switch (w) {
            case 0: src = wq; dst = Wqkv;                break;
            case 1: src = wk; dst = Wqkv + 1048576;      break;
            case 2: src = wv; dst = Wqkv + 2097152;      break;
            case 3: src = pq; dst = Pqkv;                break;
            case 4: src = pk; dst = Pqkv + 1048576;      break;
            case 5: src = pv; dst = Pqkv + 2097152;      break;
            case 6: src = wg; dst = Wg;                  break;
            default: src = wo; dst = Wo;                 break;
        }
        const float4* p = (const float4*)(src + i);
        float4 a = p[0], b = p[1];
        short8 o;
        o[0] = f2bf(a.x); o[1] = f2bf(a.y); o[2] = f2bf(a.z); o[3] = f2bf(a.w);
        o[4] = f2bf(b.x); o[5] = f2bf(b.y); o[6] = f2bf(b.z); o[7] = f2bf(b.w);
        *(short8*)(dst + i) = o;
    } else if (bid < 4120) {
        const int idx = (bid - 4096) * 256 + t;  // 6144
        const int sel = idx >> 10, j = idx & 1023;
        const float* s;
        switch (sel) {
            case 0: s = bq; break; case 1: s = bk; break; case 2: s = bv; break;
            case 3: s = pqb; break; case 4: s = pkb; break; default: s = pvb; break;
        }
        float v = s[j];
        if (sel < 3) bqkv[sel * 1024 + j] = v;
        else         bpw[(sel - 3) * 1024 + j] = v;
    } else if (bid < 4376) {
        const int tt = bid - 4120;               // 0..255 -> 16x16 tiles
        const int r0 = (tt >> 4) * 64, c0 = (tt & 15) * 64;
#pragma unroll
        for (int i = 0; i < 16; i++) {
            int lin = i * 256 + t; int lr = lin >> 6, lc = lin & 63;
            tile[lr][lc] = memw[(long long)(r0 + lr) * DD + (c0 + lc)];
        }
        __syncthreads();
#pragma unroll
        for (int i = 0; i < 16; i++) {
            int lin = i * 256 + t; int orr = lin >> 6, oc = lin & 63;
            MwT[(long long)(c0 + orr) * DD + (r0 + oc)] = f2bf(tile[oc][orr]);
        }
    } else if (bid < 8472) {
        const long long i = (long long)((bid - 4376) * 256 + t) * 8;
        const float4* p = (const float4*)(x + i);
        float4 a = p[0], b = p[1];
        short8 o;
        o[0] = f2bf(a.x); o[1] = f2bf(a.y); o[2] = f2bf(a.z); o[3] = f2bf(a.w);
        o[4] = f2bf(b.x); o[5] = f2bf(b.y); o[6] = f2bf(b.z); o[7] = f2bf(b.w);
        *(short8*)(xb + i) = o;
    } else if (bid == 8472) {
        if (t == 0) *loss = 0.f;
    } else {
        rsum[(bid - 8473) * 256 + t] = 0.f;
    }
}

// fused depthwise conv over L (k=3, pad 1) + bias, all 3 branches.
__global__ __launch_bounds__(256) void k_dwconv3b(const short* __restrict__ in,
                                                  const float* __restrict__ dwq,
                                                  const float* __restrict__ dwk,
                                                  const float* __restrict__ dwv,
                                                  const float* __restrict__ dbq,
                                                  const float* __restrict__ dbk,
                                                  const float* __restrict__ dbv,
                                                  short* __restrict__ outp) {
    const int idx = blockIdx.x * 256 + threadIdx.x;  // 3*4*256*128 = 393216
    const int d8 = idx & 127;
    const int lc = (idx >> 7) & 255;
    const int b  = (idx >> 15) & 3;
    const int br = idx >> 17;                         // uniform per block
    const float* dw = (br == 0) ? dwq : (br == 1) ? dwk : dwv;
    const float* db = (br == 0) ? dbq : (br == 1) ? dbk : dbv;

    float w[24], bb[8];
    {
        const float4* wp = (const float4*)(dw + d8 * 24);
#pragma unroll
        for (int i = 0; i < 6; i++) {
            float4 tt = wp[i];
            w[i * 4 + 0] = tt.x; w[i * 4 + 1] = tt.y;
            w[i * 4 + 2] = tt.z; w[i * 4 + 3] = tt.w;
        }
        const float4* bp = (const float4*)(db + d8 * 8);
        float4 t0 = bp[0], t1 = bp[1];
        bb[0] = t0.x; bb[1] = t0.y; bb[2] = t0.z; bb[3] = t0.w;
        bb[4] = t1.x; bb[5] = t1.y; bb[6] = t1.z; bb[7] = t1.w;
    }

    const int l0 = lc * 8;
    const long long base = ((long long)(b * LL + l0)) * 3072 + br * 1024 + d8 * 8;
    short8 xr[10];
#pragma unroll
    for (int i = 0; i < 10; i++) {
        const int l = l0 - 1 + i;
        if (l >= 0 && l < LL) xr[i] = *(const short8*)(in + base + (long long)(i - 1) * 3072);
        else { short8 z = {0, 0, 0, 0, 0, 0, 0, 0}; xr[i] = z; }
    }
#pragma unroll
    for (int j = 0; j < 8; j++) {
        short8 o;
#pragma unroll
        for (int c = 0; c < 8; c++) {
            float v = bb[c] + w[c * 3 + 0] * bf2f(xr[j][c])
                            + w[c * 3 + 1] * bf2f(xr[j + 1][c])
                            + w[c * 3 + 2] * bf2f(xr[j + 2][c]);
            o[c] = f2bf(v);
        }
        *(short8*)(outp + base + (long long)j * 3072) = o;
    }
}

// ======== k_vt_norm: V^T transpose + Q/K inverse row norms, one launch ====
__global__ __launch_bounds__(256) void k_vt_norm(const short* __restrict__ vb,
                                                 short* __restrict__ VT,
                                                 const short* __restrict__ qkb,
                                                 float* __restrict__ ninv) {
    __shared__ short tile[64][65];
    __shared__ float red[4];
    const int bid = blockIdx.x;
    const int t = threadIdx.x;
    if (bid < 2048) {
        const int z = bid >> 9, tt = bid & 511;
        const int r0 = (tt >> 4) * 64, c0 = (tt & 15) * 64;
        const short* in = vb + (long long)z * SLD;
        short* out = VT + (long long)z * SLD;
#pragma unroll
        for (int i = 0; i < 16; i++) {
            int lin = i * 256 + t; int lr = lin >> 6, lc = lin & 63;
            tile[lr][lc] = in[(long long)(r0 + lr) * 1024 + (c0 + lc)];
        }
        __syncthreads();
#pragma unroll
        for (int i = 0; i < 16; i++) {
            int lin = i * 256 + t; int orr = lin >> 6, oc = lin & 63;
            out[(long long)(c0 + orr) * 2048 + (r0 + oc)] = tile[oc][orr];
        }
    } else {
        const long long row = bid - 2048;
        const short* p = qkb + row * DD;
        short4v v = *(const short4v*)(p + t * 4);
        float f0 = bf2f(v[0]), f1 = bf2f(v[1]), f2 = bf2f(v[2]), f3 = bf2f(v[3]);
        float ss = f0 * f0 + f1 * f1 + f2 * f2 + f3 * f3;
        ss = waveSum(ss);
        if ((t & 63) == 0) red[t >> 6] = ss;
        __syncthreads();
        ss = (red[0] + red[1]) + (red[2] + red[3]);
        if (t == 0) ninv[row] = 1.f / fmaxf(sqrtf(ss), 1e-12f);
    }
}

// in-place layernorm on fp32 rows of 1024
__global__ __launch_bounds__(256) void k_layernorm(float* __restrict__ y,
                                                   const float* __restrict__ g,
                                                   const float* __restrict__ b) {
    __shared__ float redS[4], redQ[4];
    const long long row = blockIdx.x;
    float* p = y + row * DD;
    const int t = threadIdx.x;
    float4 v = *(float4*)(p + t * 4);
    float s = v.x + v.y + v.z + v.w;
    float q = v.x * v.x + v.y * v.y + v.z * v.z + v.w * v.w;
    s = waveSum(s); q = waveSum(q);
    if ((t & 63) == 0) { redS[t >> 6] = s; redQ[t >> 6] = q; }
    __syncthreads();
    s = (redS[0] + redS[1]) + (redS[2] + redS[3]);
    q = (redQ[0] + redQ[1]) + (redQ[2] + redQ[3]);
    float mu = s * (1.f / DD);
    float var = q * (1.f / DD) - mu * mu;
    float rs = rsqrtf(var + 1e-5f);
    float4 o;
    o.x = (v.x - mu) * rs * g[t * 4 + 0] + b[t * 4 + 0];
    o.y = (v.y - mu) * rs * g[t * 4 + 1] + b[t * 4 + 1];
    o.z = (v.z - mu) * rs * g[t * 4 + 2] + b[t * 4 + 2];
    o.w = (v.w - mu) * rs * g[t * 4 + 3] + b[t * 4 + 3];
    *(float4*)(p + t * 4) = o;
}

enum { EPI_SILU, EPI_BIAS, EPI_EXPS, EPI_GATE, EPI_RESID };

// ======== R11 unified GEMM: 128x128 tile, BK=64, single buffer, 4 blk/CU ==
// (proven optimum of this family; R12-R14: do not perturb.)
// EPI_EXPS: P = exp((A@W^T)*qinv[r]*kinv[c]/32); ALSO accumulates fp32 row
// sums of P into rsum via 4x shfl_xor (16 col-lanes) + one atomicAdd per
// row per wave — replaces the separate 134 MB rowsum pass.
template <int EPI>
__global__ __launch_bounds__(256, 4) void gemm(
    const short* __restrict__ A, int lda, long long sAb,
    const short* __restrict__ W, int ldw, long long sWb,
    void* __restrict__ outv, int ldo, long long sOb,
    const float* __restrict__ bias, long long sBias,
    const void* __restrict__ aux,
    int K, float scale, float* __restrict__ rsum) {
    __shared__ short lds[16384];       // A 8192 + B 8192 shorts = 32 KiB

    const int z = blockIdx.z;
    A += (long long)z * sAb;
    W += (long long)z * sWb;

    const int tid = threadIdx.x;
    const int wid = tid >> 6, lane = tid & 63;
    const int row0 = blockIdx.y * 128, col0 = blockIdx.x * 128;
    const int wrM = (wid >> 1) * 64, wcN = (wid & 1) * 64;
    const int rl = lane & 15, kcl = lane >> 4;

    f32x4 acc[4][4] = {};

    const int srow = tid >> 3;                       // 0..31
    const int cswz = (tid & 7) ^ (srow & 7);
    long long offA[4], offB[4];
#pragma unroll
    for (int j = 0; j < 4; j++) {
        const int rr = j * 32 + srow;                // row&7 == srow&7
        offA[j] = (long long)(row0 + rr) * lda + cswz * 8;
        offB[j] = (long long)(col0 + rr) * ldw + cswz * 8;
    }

    const int nk = K >> 6;
    const int swz0 = (kcl ^ (rl & 7)) * 8;
    const int swz1 = ((kcl + 4) ^ (rl & 7)) * 8;

    for (int t = 0; t < nk; ++t) {
        const short* a = A + (long long)t * 64;
        const short* w = W + (long long)t * 64;
#pragma unroll
        for (int j = 0; j < 4; j++)
            gload16(a + offA[j], lds + (j * 256 + tid) * 8);
#pragma unroll
        for (int j = 0; j < 4; j++)
            gload16(w + offB[j], lds + 8192 + (j * 256 + tid) * 8);
        asm volatile("s_waitcnt vmcnt(0)" ::: "memory");
        __builtin_amdgcn_s_barrier();

        short8 af[4], bfr[4];
#pragma unroll
        for (int mi = 0; mi < 4; mi++)
            af[mi] = *(const short8*)&lds[(wrM + mi * 16 + rl) * 64 + swz0];
#pragma unroll
        for (int ni = 0; ni < 4; ni++)
            bfr[ni] = *(const short8*)&lds[8192 + (wcN + ni * 16 + rl) * 64 + swz0];
        __builtin_amdgcn_s_setprio(1);
#pragma unroll
        for (int mi = 0; mi < 4; mi++)
#pragma unroll
            for (int ni = 0; ni < 4; ni++)
                acc[mi][ni] = __builtin_amdgcn_mfma_f32_16x16x32_bf16(
                    af[mi], bfr[ni], acc[mi][ni], 0, 0, 0);
        __builtin_amdgcn_s_setprio(0);
#pragma unroll
        for (int mi = 0; mi < 4; mi++)
            af[mi] = *(const short8*)&lds[(wrM + mi * 16 + rl) * 64 + swz1];
#pragma unroll
        for (int ni = 0; ni < 4; ni++)
            bfr[ni] = *(const short8*)&lds[8192 + (wcN + ni * 16 + rl) * 64 + swz1];
        __builtin_amdgcn_s_setprio(1);
#pragma unroll
        for (int mi = 0; mi < 4; mi++)
#pragma unroll
            for (int ni = 0; ni < 4; ni++)
                acc[mi][ni] = __builtin_amdgcn_mfma_f32_16x16x32_bf16(
                    af[mi], bfr[ni], acc[mi][ni], 0, 0, 0);
        __builtin_amdgcn_s_setprio(0);
        __builtin_amdgcn_s_barrier();    // all reads of tile t done before t+1 stages
    }

    // epilogue: C/D layout col=lane&15, row=(lane>>4)*4+r  [m89/m91-verified]
    const int lr4 = (lane >> 4) * 4;
    if constexpr (EPI == EPI_EXPS) {
        const float* qz = bias + (long long)z * sBias;
        const float* kz = (const float*)aux + (long long)z * 2048;
        float* rs = rsum + (long long)z * 2048;
        short* op = (short*)outv + (long long)z * sOb;
        float kc4[4];
#pragma unroll
        for (int ni = 0; ni < 4; ni++) kc4[ni] = kz[col0 + wcN + ni * 16 + rl];
#pragma unroll
        for (int mi = 0; mi < 4; mi++) {
            float ps[4] = {0.f, 0.f, 0.f, 0.f};
#pragma unroll
            for (int ni = 0; ni < 4; ni++) {
                const int gc = col0 + wcN + ni * 16 + rl;
#pragma unroll
                for (int r = 0; r < 4; r++) {
                    const int gr = row0 + wrM + mi * 16 + lr4 + r;
                    float p = __expf(acc[mi][ni][r] * qz[gr] * kc4[ni] * scale);
                    op[(long long)gr * ldo + gc] = f2bf(p);
                    ps[r] += p;
                }
            }
#pragma unroll
            for (int r = 0; r < 4; r++) {
                float v = ps[r];
                v += __shfl_xor(v, 1);
                v += __shfl_xor(v, 2);
                v += __shfl_xor(v, 4);
                v += __shfl_xor(v, 8);
                if ((lane & 15) == 0)
                    atomicAdd(&rs[row0 + wrM + mi * 16 + lr4 + r], v);
            }
        }
    } else {
        float bcol[4];
        const float* bz = bias + (long long)z * sBias;
#pragma unroll
        for (int ni = 0; ni < 4; ni++) bcol[ni] = bz[col0 + wcN + ni * 16 + rl];
#pragma unroll
        for (int mi = 0; mi < 4; mi++) {
#pragma unroll
            for (int ni = 0; ni < 4; ni++) {
                const int gc = col0 + wcN + ni * 16 + rl;
#pragma unroll
                for (int r = 0; r < 4; r++) {
                    const int gr = row0 + wrM + mi * 16 + lr4 + r;
                    const long long oi = (long long)gr * ldo + gc;
                    float v = acc[mi][ni][r];
                    if constexpr (EPI == EPI_SILU) {
                        v += bcol[ni];
                        v = v / (1.f + __expf(-v));
                        ((short*)outv + (long long)z * sOb)[oi] = f2bf(v);
                    } else if constexpr (EPI == EPI_BIAS) {
                        ((short*)outv + (long long)z * sOb)[oi] = f2bf(v + bcol[ni]);
                    } else if constexpr (EPI == EPI_GATE) {
                        float g = 1.f / (1.f + __expf(-(v + bcol[ni])));
                        float a = bf2f(((const short*)aux)[oi]);
                        ((short*)outv)[oi] = f2bf(g * a);
                    } else if constexpr (EPI == EPI_RESID) {
                        ((float*)outv)[oi] = v + bcol[ni] + ((const float*)aux)[oi];
                    }
                }
            }
        }
    }
}

// ======== merged attn@V + mem_loss dispatch, XCD-swizzled (T1) ===========
// xcd = bid&7 (round-robin XCD assignment), j = bid>>3.
// j<64  (attn): strip = xcd*8 + (j>>3) in [0,64); z = strip>>4,
//               row0 = (strip&15)*128, col0 = (j&7)*128.
//   -> all 8 col-blocks of a P-strip land on ONE XCD; each XCD works on
//      one batch's P (8.4 MB streamed) + VT[z] (4.2 MB, 8x reuse in L2).
// j>=64 (mem_loss): strip = xcd*8 + ((j-64)>>3); row0 = strip*128,
//               col0 = ((j-64)&7)*128.
// attn: attn_out = (P@VT) / rsum[row];  ml: sum(((kb@MwT)*kinv - vb)^2).
__global__ __launch_bounds__(256, 4) void k_avml(
    const short* __restrict__ P, const short* __restrict__ VT,
    const float* __restrict__ rsum, short* __restrict__ aob,
    const short* __restrict__ kb, const short* __restrict__ MwT,
    const short* __restrict__ vb, const float* __restrict__ kinv,
    float* __restrict__ lossOut) {
    __shared__ short lds[16384];

    const int bid = blockIdx.x;
    const int xcd = bid & 7, j = bid >> 3;
    const bool isAV = j < 64;
    const short* A; const short* W;
    int lda, ldw, K, row0, col0;
    const float* rp = nullptr;
    short* outp = nullptr;
    if (isAV) {
        const int strip = xcd * 8 + (j >> 3);      // 0..63
        const int z = strip >> 4;
        row0 = (strip & 15) * 128; col0 = (j & 7) * 128;
        A = P + (long long)z * SLLB;  lda = 2048;
        W = VT + (long long)z * SLD;  ldw = 2048;
        K = 2048;
        outp = aob + (long long)z * SLD;
        rp = rsum + z * 2048;
    } else {
        const int jj = j - 64;
        const int strip = xcd * 8 + (jj >> 3);     // 0..63
        row0 = strip * 128; col0 = (jj & 7) * 128;
        A = kb; lda = 1024; W = MwT; ldw = 1024; K = 1024;
    }

    const int tid = threadIdx.x;
    const int wid = tid >> 6, lane = tid & 63;
    const int wrM = (wid >> 1) * 64, wcN = (wid & 1) * 64;
    const int rl = lane & 15, kcl = lane >> 4;

    f32x4 acc[4][4] = {};

    const int srow = tid >> 3;
    const int cswz = (tid & 7) ^ (srow & 7);
    long long offA[4], offB[4];
#pragma unroll
    for (int jj = 0; jj < 4; jj++) {
        const int rr = jj * 32 + srow;
        offA[jj] = (long long)(row0 + rr) * lda + cswz * 8;
        offB[jj] = (long long)(col0 + rr) * ldw + cswz * 8;
    }

    const int nk = K >> 6;
    const int swz0 = (kcl ^ (rl & 7)) * 8;
    const int swz1 = ((kcl + 4) ^ (rl & 7)) * 8;

    for (int t = 0; t < nk; ++t) {
        const short* a = A + (long long)t * 64;
        const short* w = W + (long long)t * 64;
#pragma unroll
        for (int jj = 0; jj < 4; jj++)
            gload16(a + offA[jj], lds + (jj * 256 + tid) * 8);
#pragma unroll
        for (int jj = 0; jj < 4; jj++)
            gload16(w + offB[jj], lds + 8192 + (jj * 256 + tid) * 8);
        asm volatile("s_waitcnt vmcnt(0)" ::: "memory");
        __builtin_amdgcn_s_barrier();

        short8 af[4], bfr[4];
#pragma unroll
        for (int mi = 0; mi < 4; mi++)
            af[mi] = *(const short8*)&lds[(wrM + mi * 16 + rl) * 64 + swz0];
#pragma unroll
        for (int ni = 0; ni < 4; ni++)
            bfr[ni] = *(const short8*)&lds[8192 + (wcN + ni * 16 + rl) * 64 + swz0];
        __builtin_amdgcn_s_setprio(1);
#pragma unroll
        for (int mi = 0; mi < 4; mi++)
#pragma unroll
            for (int ni = 0; ni < 4; ni++)
                acc[mi][ni] = __builtin_amdgcn_mfma_f32_16x16x32_bf16(
                    af[mi], bfr[ni], acc[mi][ni], 0, 0, 0);
        __builtin_amdgcn_s_setprio(0);
#pragma unroll
        for (int mi = 0; mi < 4; mi++)
            af[mi] = *(const short8*)&lds[(wrM + mi * 16 + rl) * 64 + swz1];
#pragma unroll
        for (int ni = 0; ni < 4; ni++)
            bfr[ni] = *(const short8*)&lds[8192 + (wcN + ni * 16 + rl) * 64 + swz1];
        __builtin_amdgcn_s_setprio(1);
#pragma unroll
        for (int mi = 0; mi < 4; mi++)
#pragma unroll
            for (int ni = 0; ni < 4; ni++)
                acc[mi][ni] = __builtin_amdgcn_mfma_f32_16x16x32_bf16(
                    af[mi], bfr[ni], acc[mi][ni], 0, 0, 0);
        __builtin_amdgcn_s_setprio(0);
        __builtin_amdgcn_s_barrier();
    }

    const int lr4 = (lane >> 4) * 4;
    if (isAV) {
#pragma unroll
        for (int mi = 0; mi < 4; mi++) {
#pragma unroll
            for (int ni = 0; ni < 4; ni++) {
                const int gc = col0 + wcN + ni * 16 + rl;
#pragma unroll
                for (int r = 0; r < 4; r++) {
                    const int gr = row0 + wrM + mi * 16 + lr4 + r;
                    outp[(long long)gr * 1024 + gc] = f2bf(acc[mi][ni][r] / rp[gr]);
                }
            }
        }
    } else {
        float lsum = 0.f;
#pragma unroll
        for (int mi = 0; mi < 4; mi++) {
#pragma unroll
            for (int ni = 0; ni < 4; ni++) {
                const int gc = col0 + wcN + ni * 16 + rl;
#pragma unroll
                for (int r = 0; r < 4; r++) {
                    const int gr = row0 + wrM + mi * 16 + lr4 + r;
                    float dd = acc[mi][ni][r] * kinv[gr] - bf2f(vb[(long long)gr * 1024 + gc]);
                    lsum += dd * dd;
                }
            }
        }
        lsum = waveSum(lsum);
        if (lane == 0) atomicAdd(lossOut, lsum * (1.f / (float)BLD));
    }
}

// ---------------- host ----------------

extern "C" void kernel_launch(void* const* d_in, const int* in_sizes, int n_in,
                              void* d_out, int out_size, void* d_ws, size_t ws_size,
                              hipStream_t stream) {
    const float* x    = (const float*)d_in[0];
    const float* wq   = (const float*)d_in[1];
    const float* bq   = (const float*)d_in[2];
    const float* wk   = (const float*)d_in[3];
    const float* bk   = (const float*)d_in[4];
    const float* wvw  = (const float*)d_in[5];
    const float* bvv  = (const float*)d_in[6];
    const float* dwq  = (const float*)d_in[7];
    const float* dwqb = (const float*)d_in[8];
    const float* pwq  = (const float*)d_in[9];
    const float* pwqb = (const float*)d_in[10];
    const float* dwk  = (const float*)d_in[11];
    const float* dwkb = (const float*)d_in[12];
    const float* pwk  = (const float*)d_in[13];
    const float* pwkb = (const float*)d_in[14];
    const float* dwv  = (const float*)d_in[15];
    const float* dwvb = (const float*)d_in[16];
    const float* pwv  = (const float*)d_in[17];
    const float* pwvb = (const float*)d_in[18];
    const float* wg   = (const float*)d_in[19];
    const float* bg   = (const float*)d_in[20];
    const float* wo   = (const float*)d_in[21];
    const float* bo   = (const float*)d_in[22];
    const float* memw = (const float*)d_in[23];
    const float* lng  = (const float*)d_in[24];
    const float* lnb  = (const float*)d_in[25];

    float* out = (float*)d_out;
    float* loss = out + BLD;

    char* base = (char*)d_ws;
    size_t off = 0;
    auto take = [&](size_t n) -> char* {
        char* p = base + off;
        off += (n + 255) & ~(size_t)255;
        return p;
    };
    const size_t WB = (size_t)DD * DD * 2;  // 2 MB bf16 weight
    const size_t XB = (size_t)BLD * 2;      // 16.78 MB bf16 activation
    short* Wqkv = (short*)take(3 * WB);     // concat [3072][1024]
    short* Pqkv = (short*)take(3 * WB);     // concat pointwise weights
    short* Wgb  = (short*)take(WB);
    short* Wob  = (short*)take(WB);
    short* MwT  = (short*)take(WB);
    float* bqkv = (float*)take(3072 * 4);
    float* bpw  = (float*)take(3072 * 4);
    float* rsum = (float*)take(8192 * 4);   // fp32 row sums of P, [4][2048]
    float* ninv = (float*)take(16384 * 4);  // 1/|row|: qinv [8192], kinv [8192]
    short* xb   = (short*)take(XB);         // x bf16; reused as attn_out later
    short* pre  = (short*)take(3 * XB);     // QKV silu [8192][3072]; reused as qb/kb/vb
    short* post = (short*)take(3 * XB);     // conv out [8192][3072]; reused as P+VT, gated

    short* qb = pre;
    short* kb = pre + BLD;
    short* vb = pre + 2 * BLD;
    short* scores = post;            // P = exp(cos/32): [4][2048][2048] bf16
    short* VT = post + 2 * BLD;      // [4][1024][2048]
    short* aob = xb;                 // attn_out bf16 (xb dead after QKV GEMM)
    short* gated = post;             // gated bf16 (P/VT dead after attn@V)
    float* qinv = ninv;
    float* kinv = ninv + 8192;
    (void)ws_size; (void)in_sizes; (void)n_in; (void)out_size;

    const long long sLD = SLD;
    const long long sLLb = SLLB;

    // all preprocessing in one launch (incl. zeroing loss + rsum)
    k_prep<<<8505, 256, 0, stream>>>(
        x, wq, wk, wvw, pwq, pwk, pwv, wg, wo,
        bq, bk, bvv, pwqb, pwkb, pwvb, memw,
        Wqkv, Pqkv, Wgb, Wob, bqkv, bpw, MwT, xb, loss, rsum);

    // fused QKV: silu(x @ [wq;wk;wv]^T + [bq;bk;bv]) -> pre [8192][3072]
    gemm<EPI_SILU><<<dim3(24, 64, 1), 256, 0, stream>>>(
        xb, 1024, 0, Wqkv, 1024, 0, pre, 3072, 0, bqkv, 0, nullptr, 1024, 0.f, nullptr);

    // fused depthwise conv: pre -> post
    k_dwconv3b<<<1536, 256, 0, stream>>>(pre, dwq, dwk, dwv, dwqb, dwkb, dwvb, post);

    // batched pointwise: z=3 branches; out -> qb/kb/vb
    gemm<EPI_BIAS><<<dim3(8, 64, 3), 256, 0, stream>>>(
        post, 3072, 1024, Pqkv, 1024, (long long)DD * DD, qb, 1024, BLD,
        bpw, 1024, nullptr, 1024, 0.f, nullptr);

    // V^T transpose + Q/K inverse row norms in one launch
    k_vt_norm<<<18432, 256, 0, stream>>>(vb, VT, qb, ninv);

    // P = exp((Q@K^T)*qinv*kinv/32); row sums accumulated into rsum
    gemm<EPI_EXPS><<<dim3(16, 16, 4), 256, 0, stream>>>(
        qb, 1024, sLD, kb, 1024, sLD, scores, 2048, sLLb,
        qinv, 2048, kinv, 1024, 0.03125f, rsum);

    // merged: attn_out = (P @ V)/rsum  AND  mem_loss partials (XCD-swizzled)
    k_avml<<<1024, 256, 0, stream>>>(scores, VT, rsum, aob, kb, MwT, vb, kinv, loss);

    // gated = sigmoid(attn_out @ wg^T + bg) * attn_out
    gemm<EPI_GATE><<<dim3(8, 64, 1), 256, 0, stream>>>(
        aob, 1024, 0, Wgb, 1024, 0, gated, 1024, 0, bg, 0, aob, 1024, 0.f, nullptr);

    // out = gated @ wo^T + bo + x ; then LN in-place
    gemm<EPI_RESID><<<dim3(8, 64, 1), 256, 0, stream>>>(
        gated, 1024, 0, Wob, 1024, 0, out, 1024, 0, bo, 0, x, 1024, 0.f, nullptr);
    k_layernorm<<<8192, 256, 0, stream>>>(out, lng, lnb);
}

// Round 18
// 338.715 us; speedup vs baseline: 1.2900x; 1.0186x over previous
//
#include <hip/hip_runtime.h>
#include <stdint.h>

typedef __attribute__((ext_vector_type(8))) short short8;
typedef __attribute__((ext_vector_type(4))) short short4v;
typedef __attribute__((ext_vector_type(4))) float f32x4;

#define DEV static __device__ __forceinline__

static constexpr int LL = 2048;
static constexpr int DD = 1024;
static constexpr long long BLD = 8388608LL; // 4*2048*1024
static constexpr long long SLD = 2097152LL;  // 2048*1024
static constexpr long long SLLB = 4194304LL; // 2048*2048

DEV short f2bf(float f) {
    uint32_t u = __builtin_bit_cast(uint32_t, f);
    u += 0x7fffu + ((u >> 16) & 1u);   // RNE
    return (short)(u >> 16);
}
DEV float bf2f(short s) {
    uint32_t u = ((uint32_t)(uint16_t)s) << 16;
    return __builtin_bit_cast(float, u);
}

DEV float waveSum(float v) {
#pragma unroll
    for (int o = 32; o; o >>= 1) v += __shfl_down(v, o);
    return v;
}

DEV void gload16(const void* g, void* l) {
    __builtin_amdgcn_global_load_lds(
        (const __attribute__((address_space(1))) uint32_t*)(uintptr_t)g,
        (__attribute__((address_space(3))) uint32_t*)(uintptr_t)l,
        16, 0, 0);
}

// ======== k_prep: all independent preprocessing in ONE launch ========
// 0..4095: weights f32->bf16 | 4096..4119: bias concat | 4120..4375: mem_w^T
// 4376..8471: x f32->bf16 | 8472: zero loss | 8473..8504: zero rsum[8192]
// 8505..8568: zero ssq[16384]
__global__ __launch_bounds__(256) void k_prep(
    const float* __restrict__ x,
    const float* wq, const float* wk, const float* wv,
    const float* pq, const float* pk, const float* pv,
    const float* wg, const float* wo,
    const float* bq, const float* bk, const float* bv,
    const float* pqb, const float* pkb, const float* pvb,
    const float* __restrict__ memw,
    short* Wqkv, short* Pqkv, short* Wg, short* Wo,
    float* bqkv, float* bpw, short* MwT, short* xb, float* loss,
    float* rsum, float* ssq) {
    __shared__ float tile[64][65];
    const int bid = blockIdx.x;
    const int t = threadIdx.x;

    if (bid < 4096) {
        const int w = bid >> 9;
        const long long i = (long long)((bid & 511) * 256 + t) * 8;
        const float* src; short* dst;
        switch (w) {
            case 0: src = wq; dst = Wqkv;                break;
            case 1: src = wk; dst = Wqkv + 1048576;      break;
            case 2: src = wv; dst = Wqkv + 2097152;      break;
            case 3: src = pq; dst = Pqkv;                break;
            case 4: src = pk; dst = Pqkv + 1048576;      break;
            case 5: src = pv; dst = Pqkv + 2097152;      break;
            case 6: src = wg; dst = Wg;                  break;
            default: src = wo; dst = Wo;                 break;
        }
        const float4* p = (const float4*)(src + i);
        float4 a = p[0], b = p[1];
        short8 o;
        o[0] = f2bf(a.x); o[1] = f2bf(a.y); o[2] = f2bf(a.z); o[3] = f2bf(a.w);
        o[4] = f2bf(b.x); o[5] = f2bf(b.y); o[6] = f2bf(b.z); o[7] = f2bf(b.w);
        *(short8*)(dst + i) = o;
    } else if (bid < 4120) {
        const int idx = (bid - 4096) * 256 + t;  // 6144
        const int sel = idx >> 10, j = idx & 1023;
        const float* s;
        switch (sel) {
            case 0: s = bq; break; case 1: s = bk; break; case 2: s = bv; break;
            case 3: s = pqb; break; case 4: s = pkb; break; default: s = pvb; break;
        }
        float v = s[j];
        if (sel < 3) bqkv[sel * 1024 + j] = v;
        else         bpw[(sel - 3) * 1024 + j] = v;
    } else if (bid < 4376) {
        const int tt = bid - 4120;               // 0..255 -> 16x16 tiles
        const int r0 = (tt >> 4) * 64, c0 = (tt & 15) * 64;
#pragma unroll
        for (int i = 0; i < 16; i++) {
            int lin = i * 256 + t; int lr = lin >> 6, lc = lin & 63;
            tile[lr][lc] = memw[(long long)(r0 + lr) * DD + (c0 + lc)];
        }
        __syncthreads();
#pragma unroll
        for (int i = 0; i < 16; i++) {
            int lin = i * 256 + t; int orr = lin >> 6, oc = lin & 63;
            MwT[(long long)(c0 + orr) * DD + (r0 + oc)] = f2bf(tile[oc][orr]);
        }
    } else if (bid < 8472) {
        const long long i = (long long)((bid - 4376) * 256 + t) * 8;
        const float4* p = (const float4*)(x + i);
        float4 a = p[0], b = p[1];
        short8 o;
        o[0] = f2bf(a.x); o[1] = f2bf(a.y); o[2] = f2bf(a.z); o[3] = f2bf(a.w);
        o[4] = f2bf(b.x); o[5] = f2bf(b.y); o[6] = f2bf(b.z); o[7] = f2bf(b.w);
        *(short8*)(xb + i) = o;
    } else if (bid == 8472) {
        if (t == 0) *loss = 0.f;
    } else if (bid < 8505) {
        rsum[(bid - 8473) * 256 + t] = 0.f;
    } else {
        ssq[(bid - 8505) * 256 + t] = 0.f;
    }
}

// fused depthwise conv over L (k=3, pad 1) + bias, all 3 branches.
__global__ __launch_bounds__(256) void k_dwconv3b(const short* __restrict__ in,
                                                  const float* __restrict__ dwq,
                                                  const float* __restrict__ dwk,
                                                  const float* __restrict__ dwv,
                                                  const float* __restrict__ dbq,
                                                  const float* __restrict__ dbk,
                                                  const float* __restrict__ dbv,
                                                  short* __restrict__ outp) {
    const int idx = blockIdx.x * 256 + threadIdx.x;  // 3*4*256*128 = 393216
    const int d8 = idx & 127;
    const int lc = (idx >> 7) & 255;
    const int b  = (idx >> 15) & 3;
    const int br = idx >> 17;                         // uniform per block
    const float* dw = (br == 0) ? dwq : (br == 1) ? dwk : dwv;
    const float* db = (br == 0) ? dbq : (br == 1) ? dbk : dbv;

    float w[24], bb[8];
    {
        const float4* wp = (const float4*)(dw + d8 * 24);
#pragma unroll
        for (int i = 0; i < 6; i++) {
            float4 tt = wp[i];
            w[i * 4 + 0] = tt.x; w[i * 4 + 1] = tt.y;
            w[i * 4 + 2] = tt.z; w[i * 4 + 3] = tt.w;
        }
        const float4* bp = (const float4*)(db + d8 * 8);
        float4 t0 = bp[0], t1 = bp[1];
        bb[0] = t0.x; bb[1] = t0.y; bb[2] = t0.z; bb[3] = t0.w;
        bb[4] = t1.x; bb[5] = t1.y; bb[6] = t1.z; bb[7] = t1.w;
    }

    const int l0 = lc * 8;
    const long long base = ((long long)(b * LL + l0)) * 3072 + br * 1024 + d8 * 8;
    short8 xr[10];
#pragma unroll
    for (int i = 0; i < 10; i++) {
        const int l = l0 - 1 + i;
        if (l >= 0 && l < LL) xr[i] = *(const short8*)(in + base + (long long)(i - 1) * 3072);
        else { short8 z = {0, 0, 0, 0, 0, 0, 0, 0}; xr[i] = z; }
    }
#pragma unroll
    for (int j = 0; j < 8; j++) {
        short8 o;
#pragma unroll
        for (int c = 0; c < 8; c++) {
            float v = bb[c] + w[c * 3 + 0] * bf2f(xr[j][c])
                            + w[c * 3 + 1] * bf2f(xr[j + 1][c])
                            + w[c * 3 + 2] * bf2f(xr[j + 2][c]);
            o[c] = f2bf(v);
        }
        *(short8*)(outp + base + (long long)j * 3072) = o;
    }
}

// ======== k_vt: V^T transpose only (norms folded into pw epilogue) ========
__global__ __launch_bounds__(256) void k_vt(const short* __restrict__ vb,
                                            short* __restrict__ VT) {
    __shared__ short tile[64][65];
    const int bid = blockIdx.x;
    const int t = threadIdx.x;
    const int z = bid >> 9, tt = bid & 511;
    const int r0 = (tt >> 4) * 64, c0 = (tt & 15) * 64;
    const short* in = vb + (long long)z * SLD;
    short* out = VT + (long long)z * SLD;
#pragma unroll
    for (int i = 0; i < 16; i++) {
        int lin = i * 256 + t; int lr = lin >> 6, lc = lin & 63;
        tile[lr][lc] = in[(long long)(r0 + lr) * 1024 + (c0 + lc)];
    }
    __syncthreads();
#pragma unroll
    for (int i = 0; i < 16; i++) {
        int lin = i * 256 + t; int orr = lin >> 6, oc = lin & 63;
        out[(long long)(c0 + orr) * 2048 + (r0 + oc)] = tile[oc][orr];
    }
}

// in-place layernorm on fp32 rows of 1024
__global__ __launch_bounds__(256) void k_layernorm(float* __restrict__ y,
                                                   const float* __restrict__ g,
                                                   const float* __restrict__ b) {
    __shared__ float redS[4], redQ[4];
    const long long row = blockIdx.x;
    float* p = y + row * DD;
    const int t = threadIdx.x;
    float4 v = *(float4*)(p + t * 4);
    float s = v.x + v.y + v.z + v.w;
    float q = v.x * v.x + v.y * v.y + v.z * v.z + v.w * v.w;
    s = waveSum(s); q = waveSum(q);
    if ((t & 63) == 0) { redS[t >> 6] = s; redQ[t >> 6] = q; }
    __syncthreads();
    s = (redS[0] + redS[1]) + (redS[2] + redS[3]);
    q = (redQ[0] + redQ[1]) + (redQ[2] + redQ[3]);
    float mu = s * (1.f / DD);
    float var = q * (1.f / DD) - mu * mu;
    float rs = rsqrtf(var + 1e-5f);
    float4 o;
    o.x = (v.x - mu) * rs * g[t * 4 + 0] + b[t * 4 + 0];
    o.y = (v.y - mu) * rs * g[t * 4 + 1] + b[t * 4 + 1];
    o.z = (v.z - mu) * rs * g[t * 4 + 2] + b[t * 4 + 2];
    o.w = (v.w - mu) * rs * g[t * 4 + 3] + b[t * 4 + 3];
    *(float4*)(p + t * 4) = o;
}

enum { EPI_SILU, EPI_PWQK, EPI_EXPS, EPI_GATE, EPI_RESID };

// ======== R11 unified GEMM + T1 XCD strip-chunk swizzle (template) =======
// Core loop: proven R11 optimum (128x128, BK=64, single buffer, 4 blk/CU,
// conflict-free swizzle) — do not perturb (R12-R14).
// XCD=true: bijective remap so each XCD (bid&7, round-robin dispatch) owns
// nb/(8*gx) complete A-strips with all gx col-blocks -> A-strip reads become
// same-XCD L2 hits (mechanism PMC-proven on k_avml in R17: FETCH 215->drop).
// EPI_PWQK: bias add + per-row sum-of-squares (bf16-rounded) atomically
// accumulated into ssq[z*8192+row] for z<2 (q,k) — replaces k_vt_norm half.
// EPI_EXPS: P = exp(v / sqrt(ssq_q[r]) / sqrt(ssq_k[c]) / 32) + row sums.
template <int EPI, bool XCD>
__global__ __launch_bounds__(256, 4) void gemm(
    const short* __restrict__ A, int lda, long long sAb,
    const short* __restrict__ W, int ldw, long long sWb,
    void* __restrict__ outv, int ldo, long long sOb,
    const float* __restrict__ bias, long long sBias,
    const void* __restrict__ aux,
    int K, float scale, float* __restrict__ rsum) {
    __shared__ short lds[16384];       // A 8192 + B 8192 shorts = 32 KiB

    int bx = blockIdx.x, by = blockIdx.y, bz = blockIdx.z;
    if constexpr (XCD) {
        const int gx = gridDim.x, gy = gridDim.y;
        const int nb = gx * gy * gridDim.z;
        const int bid = bx + gx * (by + gy * bz);
        const int xcd = bid & 7, r = bid >> 3;
        const int spx = nb / (8 * gx);          // strips per XCD
        const int sl = r / gx, cb = r - sl * gx;
        const int sg = xcd * spx + sl;
        bx = cb; by = sg % gy; bz = sg / gy;
    }
    const int z = bz;
    A += (long long)z * sAb;
    W += (long long)z * sWb;

    const int tid = threadIdx.x;
    const int wid = tid >> 6, lane = tid & 63;
    const int row0 = by * 128, col0 = bx * 128;
    const int wrM = (wid >> 1) * 64, wcN = (wid & 1) * 64;
    const int rl = lane & 15, kcl = lane >> 4;

    f32x4 acc[4][4] = {};

    const int srow = tid >> 3;                       // 0..31
    const int cswz = (tid & 7) ^ (srow & 7);
    long long offA[4], offB[4];
#pragma unroll
    for (int j = 0; j < 4; j++) {
        const int rr = j * 32 + srow;                // row&7 == srow&7
        offA[j] = (long long)(row0 + rr) * lda + cswz * 8;
        offB[j] = (long long)(col0 + rr) * ldw + cswz * 8;
    }

    const int nk = K >> 6;
    const int swz0 = (kcl ^ (rl & 7)) * 8;
    const int swz1 = ((kcl + 4) ^ (rl & 7)) * 8;

    for (int t = 0; t < nk; ++t) {
        const short* a = A + (long long)t * 64;
        const short* w = W + (long long)t * 64;
#pragma unroll
        for (int j = 0; j < 4; j++)
            gload16(a + offA[j], lds + (j * 256 + tid) * 8);
#pragma unroll
        for (int j = 0; j < 4; j++)
            gload16(w + offB[j], lds + 8192 + (j * 256 + tid) * 8);
        asm volatile("s_waitcnt vmcnt(0)" ::: "memory");
        __builtin_amdgcn_s_barrier();

        short8 af[4], bfr[4];
#pragma unroll
        for (int mi = 0; mi < 4; mi++)
            af[mi] = *(const short8*)&lds[(wrM + mi * 16 + rl) * 64 + swz0];
#pragma unroll
        for (int ni = 0; ni < 4; ni++)
            bfr[ni] = *(const short8*)&lds[8192 + (wcN + ni * 16 + rl) * 64 + swz0];
        __builtin_amdgcn_s_setprio(1);
#pragma unroll
        for (int mi = 0; mi < 4; mi++)
#pragma unroll
            for (int ni = 0; ni < 4; ni++)
                acc[mi][ni] = __builtin_amdgcn_mfma_f32_16x16x32_bf16(
                    af[mi], bfr[ni], acc[mi][ni], 0, 0, 0);
        __builtin_amdgcn_s_setprio(0);
#pragma unroll
        for (int mi = 0; mi < 4; mi++)
            af[mi] = *(const short8*)&lds[(wrM + mi * 16 + rl) * 64 + swz1];
#pragma unroll
        for (int ni = 0; ni < 4; ni++)
            bfr[ni] = *(const short8*)&lds[8192 + (wcN + ni * 16 + rl) * 64 + swz1];
        __builtin_amdgcn_s_setprio(1);
#pragma unroll
        for (int mi = 0; mi < 4; mi++)
#pragma unroll
            for (int ni = 0; ni < 4; ni++)
                acc[mi][ni] = __builtin_amdgcn_mfma_f32_16x16x32_bf16(
                    af[mi], bfr[ni], acc[mi][ni], 0, 0, 0);
        __builtin_amdgcn_s_setprio(0);
        __builtin_amdgcn_s_barrier();    // all reads of tile t done before t+1 stages
    }

    // epilogue: C/D layout col=lane&15, row=(lane>>4)*4+r  [m89/m91-verified]
    const int lr4 = (lane >> 4) * 4;
    if constexpr (EPI == EPI_EXPS) {
        const float* qz = bias + (long long)z * sBias;       // ssq_q
        const float* kz = (const float*)aux + (long long)z * 2048;  // ssq_k
        float* rs = rsum + (long long)z * 2048;
        short* op = (short*)outv + (long long)z * sOb;
        float kc4[4];
#pragma unroll
        for (int ni = 0; ni < 4; ni++) {
            float ss = kz[col0 + wcN + ni * 16 + rl];
            kc4[ni] = 1.f / fmaxf(sqrtf(ss), 1e-12f);
        }
#pragma unroll
        for (int mi = 0; mi < 4; mi++) {
            float ps[4] = {0.f, 0.f, 0.f, 0.f};
#pragma unroll
            for (int r = 0; r < 4; r++) {
                // cache 1/sqrt(ssq_q) per row (shared across ni)
                const int gr = row0 + wrM + mi * 16 + lr4 + r;
                float qv = 1.f / fmaxf(sqrtf(qz[gr]), 1e-12f);
#pragma unroll
                for (int ni = 0; ni < 4; ni++) {
                    const int gc = col0 + wcN + ni * 16 + rl;
                    float p = __expf(acc[mi][ni][r] * qv * kc4[ni] * scale);
                    op[(long long)gr * ldo + gc] = f2bf(p);
                    ps[r] += p;
                }
            }
#pragma unroll
            for (int r = 0; r < 4; r++) {
                float v = ps[r];
                v += __shfl_xor(v, 1);
                v += __shfl_xor(v, 2);
                v += __shfl_xor(v, 4);
                v += __shfl_xor(v, 8);
                if ((lane & 15) == 0)
                    atomicAdd(&rs[row0 + wrM + mi * 16 + lr4 + r], v);
            }
        }
    } else {
        float bcol[4];
        const float* bz = bias + (long long)z * sBias;
#pragma unroll
        for (int ni = 0; ni < 4; ni++) bcol[ni] = bz[col0 + wcN + ni * 16 + rl];
#pragma unroll
        for (int mi = 0; mi < 4; mi++) {
            float ps[4] = {0.f, 0.f, 0.f, 0.f};
#pragma unroll
            for (int ni = 0; ni < 4; ni++) {
                const int gc = col0 + wcN + ni * 16 + rl;
#pragma unroll
                for (int r = 0; r < 4; r++) {
                    const int gr = row0 + wrM + mi * 16 + lr4 + r;
                    const long long oi = (long long)gr * ldo + gc;
                    float v = acc[mi][ni][r];
                    if constexpr (EPI == EPI_SILU) {
                        v += bcol[ni];
                        v = v / (1.f + __expf(-v));
                        ((short*)outv + (long long)z * sOb)[oi] = f2bf(v);
                    } else if constexpr (EPI == EPI_PWQK) {
                        short h = f2bf(v + bcol[ni]);
                        ((short*)outv + (long long)z * sOb)[oi] = h;
                        float vr = bf2f(h);
                        ps[r] += vr * vr;
                    } else if constexpr (EPI == EPI_GATE) {
                        float g = 1.f / (1.f + __expf(-(v + bcol[ni])));
                        float a = bf2f(((const short*)aux)[oi]);
                        ((short*)outv)[oi] = f2bf(g * a);
                    } else if constexpr (EPI == EPI_RESID) {
                        ((float*)outv)[oi] = v + bcol[ni] + ((const float*)aux)[oi];
                    }
                }
            }
            if constexpr (EPI == EPI_PWQK) {
                if (z < 2) {
                    float* sq = rsum + (long long)z * 8192;
#pragma unroll
                    for (int r = 0; r < 4; r++) {
                        float v = ps[r];
                        v += __shfl_xor(v, 1);
                        v += __shfl_xor(v, 2);
                        v += __shfl_xor(v, 4);
                        v += __shfl_xor(v, 8);
                        if ((lane & 15) == 0)
                            atomicAdd(&sq[row0 + wrM + mi * 16 + lr4 + r], v);
                    }
                }
            }
        }
    }
}

// ======== merged attn@V + mem_loss dispatch, XCD-swizzled (T1) ===========
__global__ __launch_bounds__(256, 4) void k_avml(
    const short* __restrict__ P, const short* __restrict__ VT,
    const float* __restrict__ rsum, short* __restrict__ aob,
    const short* __restrict__ kb, const short* __restrict__ MwT,
    const short* __restrict__ vb, const float* __restrict__ ssk,
    float* __restrict__ lossOut) {
    __shared__ short lds[16384];

    const int bid = blockIdx.x;
    const int xcd = bid & 7, j = bid >> 3;
    const bool isAV = j < 64;
    const short* A; const short* W;
    int lda, ldw, K, row0, col0;
    const float* rp = nullptr;
    short* outp = nullptr;
    if (isAV) {
        const int strip = xcd * 8 + (j >> 3);      // 0..63
        const int z = strip >> 4;
        row0 = (strip & 15) * 128; col0 = (j & 7) * 128;
        A = P + (long long)z * SLLB;  lda = 2048;
        W = VT + (long long)z * SLD;  ldw = 2048;
        K = 2048;
        outp = aob + (long long)z * SLD;
        rp = rsum + z * 2048;
    } else {
        const int jj = j - 64;
        const int strip = xcd * 8 + (jj >> 3);     // 0..63
        row0 = strip * 128; col0 = (jj & 7) * 128;
        A = kb; lda = 1024; W = MwT; ldw = 1024; K = 1024;
    }

    const int tid = threadIdx.x;
    const int wid = tid >> 6, lane = tid & 63;
    const int wrM = (wid >> 1) * 64, wcN = (wid & 1) * 64;
    const int rl = lane & 15, kcl = lane >> 4;

    f32x4 acc[4][4] = {};

    const int srow = tid >> 3;
    const int cswz = (tid & 7) ^ (srow & 7);
    long long offA[4], offB[4];
#pragma unroll
    for (int jj = 0; jj < 4; jj++) {
        const int rr = jj * 32 + srow;
        offA[jj] = (long long)(row0 + rr) * lda + cswz * 8;
        offB[jj] = (long long)(col0 + rr) * ldw + cswz * 8;
    }

    const int nk = K >> 6;
    const int swz0 = (kcl ^ (rl & 7)) * 8;
    const int swz1 = ((kcl + 4) ^ (rl & 7)) * 8;

    for (int t = 0; t < nk; ++t) {
        const short* a = A + (long long)t * 64;
        const short* w = W + (long long)t * 64;
#pragma unroll
        for (int jj = 0; jj < 4; jj++)
            gload16(a + offA[jj], lds + (jj * 256 + tid) * 8);
#pragma unroll
        for (int jj = 0; jj < 4; jj++)
            gload16(w + offB[jj], lds + 8192 + (jj * 256 + tid) * 8);
        asm volatile("s_waitcnt vmcnt(0)" ::: "memory");
        __builtin_amdgcn_s_barrier();

        short8 af[4], bfr[4];
#pragma unroll
        for (int mi = 0; mi < 4; mi++)
            af[mi] = *(const short8*)&lds[(wrM + mi * 16 + rl) * 64 + swz0];
#pragma unroll
        for (int ni = 0; ni < 4; ni++)
            bfr[ni] = *(const short8*)&lds[8192 + (wcN + ni * 16 + rl) * 64 + swz0];
        __builtin_amdgcn_s_setprio(1);
#pragma unroll
        for (int mi = 0; mi < 4; mi++)
#pragma unroll
            for (int ni = 0; ni < 4; ni++)
                acc[mi][ni] = __builtin_amdgcn_mfma_f32_16x16x32_bf16(
                    af[mi], bfr[ni], acc[mi][ni], 0, 0, 0);
        __builtin_amdgcn_s_setprio(0);
#pragma unroll
        for (int mi = 0; mi < 4; mi++)
            af[mi] = *(const short8*)&lds[(wrM + mi * 16 + rl) * 64 + swz1];
#pragma unroll
        for (int ni = 0; ni < 4; ni++)
            bfr[ni] = *(const short8*)&lds[8192 + (wcN + ni * 16 + rl) * 64 + swz1];
        __builtin_amdgcn_s_setprio(1);
#pragma unroll
        for (int mi = 0; mi < 4; mi++)
#pragma unroll
            for (int ni = 0; ni < 4; ni++)
                acc[mi][ni] = __builtin_amdgcn_mfma_f32_16x16x32_bf16(
                    af[mi], bfr[ni], acc[mi][ni], 0, 0, 0);
        __builtin_amdgcn_s_setprio(0);
        __builtin_amdgcn_s_barrier();
    }

    const int lr4 = (lane >> 4) * 4;
    if (isAV) {
#pragma unroll
        for (int mi = 0; mi < 4; mi++) {
#pragma unroll
            for (int ni = 0; ni < 4; ni++) {
                const int gc = col0 + wcN + ni * 16 + rl;
#pragma unroll
                for (int r = 0; r < 4; r++) {
                    const int gr = row0 + wrM + mi * 16 + lr4 + r;
                    outp[(long long)gr * 1024 + gc] = f2bf(acc[mi][ni][r] / rp[gr]);
                }
            }
        }
    } else {
        float lsum = 0.f;
#pragma unroll
        for (int mi = 0; mi < 4; mi++) {
#pragma unroll
            for (int r = 0; r < 4; r++) {
                const int gr = row0 + wrM + mi * 16 + lr4 + r;
                const float kiv = 1.f / fmaxf(sqrtf(ssk[gr]), 1e-12f);
#pragma unroll
                for (int ni = 0; ni < 4; ni++) {
                    const int gc = col0 + wcN + ni * 16 + rl;
                    float dd = acc[mi][ni][r] * kiv - bf2f(vb[(long long)gr * 1024 + gc]);
                    lsum += dd * dd;
                }
            }
        }
        lsum = waveSum(lsum);
        if (lane == 0) atomicAdd(lossOut, lsum * (1.f / (float)BLD));
    }
}

// ---------------- host ----------------

extern "C" void kernel_launch(void* const* d_in, const int* in_sizes, int n_in,
                              void* d_out, int out_size, void* d_ws, size_t ws_size,
                              hipStream_t stream) {
    const float* x    = (const float*)d_in[0];
    const float* wq   = (const float*)d_in[1];
    const float* bq   = (const float*)d_in[2];
    const float* wk   = (const float*)d_in[3];
    const float* bk   = (const float*)d_in[4];
    const float* wvw  = (const float*)d_in[5];
    const float* bvv  = (const float*)d_in[6];
    const float* dwq  = (const float*)d_in[7];
    const float* dwqb = (const float*)d_in[8];
    const float* pwq  = (const float*)d_in[9];
    const float* pwqb = (const float*)d_in[10];
    const float* dwk  = (const float*)d_in[11];
    const float* dwkb = (const float*)d_in[12];
    const float* pwk  = (const float*)d_in[13];
    const float* pwkb = (const float*)d_in[14];
    const float* dwv  = (const float*)d_in[15];
    const float* dwvb = (const float*)d_in[16];
    const float* pwv  = (const float*)d_in[17];
    const float* pwvb = (const float*)d_in[18];
    const float* wg   = (const float*)d_in[19];
    const float* bg   = (const float*)d_in[20];
    const float* wo   = (const float*)d_in[21];
    const float* bo   = (const float*)d_in[22];
    const float* memw = (const float*)d_in[23];
    const float* lng  = (const float*)d_in[24];
    const float* lnb  = (const float*)d_in[25];

    float* out = (float*)d_out;
    float* loss = out + BLD;

    char* base = (char*)d_ws;
    size_t off = 0;
    auto take = [&](size_t n) -> char* {
        char* p = base + off;
        off += (n + 255) & ~(size_t)255;
        return p;
    };
    const size_t WB = (size_t)DD * DD * 2;  // 2 MB bf16 weight
    const size_t XB = (size_t)BLD * 2;      // 16.78 MB bf16 activation
    short* Wqkv = (short*)take(3 * WB);     // concat [3072][1024]
    short* Pqkv = (short*)take(3 * WB);     // concat pointwise weights
    short* Wgb  = (short*)take(WB);
    short* Wob  = (short*)take(WB);
    short* MwT  = (short*)take(WB);
    float* bqkv = (float*)take(3072 * 4);
    float* bpw  = (float*)take(3072 * 4);
    float* rsum = (float*)take(8192 * 4);   // fp32 row sums of P, [4][2048]
    float* ssq  = (float*)take(16384 * 4);  // row sum-sq: q [8192], k [8192]
    short* xb   = (short*)take(XB);         // x bf16; reused as attn_out later
    short* pre  = (short*)take(3 * XB);     // QKV silu [8192][3072]; reused as qb/kb/vb
    short* post = (short*)take(3 * XB);     // conv out [8192][3072]; reused as P+VT, gated

    short* qb = pre;
    short* kb = pre + BLD;
    short* vb = pre + 2 * BLD;
    short* scores = post;            // P = exp(cos/32): [4][2048][2048] bf16
    short* VT = post + 2 * BLD;      // [4][1024][2048]
    short* aob = xb;                 // attn_out bf16 (xb dead after QKV GEMM)
    short* gated = post;             // gated bf16 (P/VT dead after attn@V)
    float* ssq_k = ssq + 8192;
    (void)ws_size; (void)in_sizes; (void)n_in; (void)out_size;

    const long long sLD = SLD;
    const long long sLLb = SLLB;

    // all preprocessing in one launch (incl. zeroing loss + rsum + ssq)
    k_prep<<<8569, 256, 0, stream>>>(
        x, wq, wk, wvw, pwq, pwk, pwv, wg, wo,
        bq, bk, bvv, pwqb, pwkb, pwvb, memw,
        Wqkv, Pqkv, Wgb, Wob, bqkv, bpw, MwT, xb, loss, rsum, ssq);

    // fused QKV: silu(x @ [wq;wk;wv]^T + [bq;bk;bv]) -> pre [8192][3072]
    gemm<EPI_SILU, true><<<dim3(24, 64, 1), 256, 0, stream>>>(
        xb, 1024, 0, Wqkv, 1024, 0, pre, 3072, 0, bqkv, 0, nullptr, 1024, 0.f, nullptr);

    // fused depthwise conv: pre -> post
    k_dwconv3b<<<1536, 256, 0, stream>>>(pre, dwq, dwk, dwv, dwqb, dwkb, dwvb, post);

    // batched pointwise: z=3 branches; out -> qb/kb/vb; ssq(q,k) accumulated
    gemm<EPI_PWQK, true><<<dim3(8, 64, 3), 256, 0, stream>>>(
        post, 3072, 1024, Pqkv, 1024, (long long)DD * DD, qb, 1024, BLD,
        bpw, 1024, nullptr, 1024, 0.f, ssq);

    // V^T transpose (norms already folded into pw epilogue)
    k_vt<<<2048, 256, 0, stream>>>(vb, VT);

    // P = exp((Q@K^T)/|q|/|k|/32); row sums accumulated into rsum
    gemm<EPI_EXPS, true><<<dim3(16, 16, 4), 256, 0, stream>>>(
        qb, 1024, sLD, kb, 1024, sLD, scores, 2048, sLLb,
        ssq, 2048, ssq_k, 1024, 0.03125f, rsum);

    // merged: attn_out = (P @ V)/rsum  AND  mem_loss partials (XCD-swizzled)
    k_avml<<<1024, 256, 0, stream>>>(scores, VT, rsum, aob, kb, MwT, vb, ssq_k, loss);

    // gated = sigmoid(attn_out @ wg^T + bg) * attn_out
    gemm<EPI_GATE, false><<<dim3(8, 64, 1), 256, 0, stream>>>(
        aob, 1024, 0, Wgb, 1024, 0, gated, 1024, 0, bg, 0, aob, 1024, 0.f, nullptr);

    // out = gated @ wo^T + bo + x ; then LN in-place
    gemm<EPI_RESID, false><<<dim3(8, 64, 1), 256, 0, stream>>>(
        gated, 1024, 0, Wob, 1024, 0, out, 1024, 0, bo, 0, x, 1024, 0.f, nullptr);
    k_layernorm<<<8192, 256, 0, stream>>>(out, lng, lnb);
}